// Round 15
// baseline (316.138 us; speedup 1.0000x reference)
//
#include <hip/hip_runtime.h>
#include <math.h>

#define N_NODES 100000
#define N_EDGES 1600000
#define DIM_IN  256
#define DIM_H   64
#define DIM_C   47
#define NB       8                            // coarse dst buckets
#define BUCKET_W 12500                        // nodes per bucket
#define BCAP     204000                       // per-bucket capacity (9.5 sigma)
#define CHUNK_P1 1024                         // edges per pass-1 block (4/thread)
#define SEG_P2   2048                         // bucket-buf segment per pass-2a block
#define NSEG_P2  100                          // segments per bucket
#define CHUNK_NODES 250                       // nodes per fine chunk
#define NCHUNK   400                          // N_NODES / 250
#define CCAP     4608                         // per-chunk edge capacity
#define XPAD     260                          // x-tile row stride in floats

typedef __attribute__((ext_vector_type(8))) short bf16x8;
typedef __attribute__((ext_vector_type(4))) float f32x4;

// RNE float -> bf16 bits
static __device__ __forceinline__ unsigned short f2bf(float f) {
  unsigned u = __builtin_bit_cast(unsigned, f);
  u += 0x7FFFu + ((u >> 16) & 1u);
  return (unsigned short)(u >> 16);
}
static __device__ __forceinline__ float bf2f(unsigned short h) {
  unsigned u = ((unsigned)h) << 16;
  return __builtin_bit_cast(float, u);
}

// ---------- zero the counters ----------
__global__ __launch_bounds__(512) void k_zero(int* __restrict__ bucket_cur,
                                              int* __restrict__ chunk_cur) {
  if (threadIdx.x < NB) bucket_cur[threadIdx.x] = 0;
  if (threadIdx.x < NCHUNK) chunk_cur[threadIdx.x] = 0;
}

// ---------- pass 1: coarse octant binning (dense reservation writes) ----------
__global__ __launch_bounds__(256) void k_bin(const int* __restrict__ src,
                                             const int* __restrict__ dst,
                                             int* __restrict__ bucket_cur,
                                             unsigned* __restrict__ bucket_buf) {
  __shared__ int lcnt[NB], lbase[NB], lcur[NB];
  if (threadIdx.x < NB) lcnt[threadIdx.x] = 0;
  __syncthreads();
  const int base = blockIdx.x * CHUNK_P1 + threadIdx.x;
  int dreg[4], sreg[4];
#pragma unroll
  for (int it = 0; it < 4; ++it) {
    int e = base + it * 256;
    int d = -1, s = 0;
    if (e < N_EDGES) { d = dst[e]; s = src[e]; }
    dreg[it] = d; sreg[it] = s;
    if (d >= 0) atomicAdd(&lcnt[d / BUCKET_W], 1);
  }
  __syncthreads();
  if (threadIdx.x < NB) {
    lbase[threadIdx.x] = atomicAdd(&bucket_cur[threadIdx.x], lcnt[threadIdx.x]);
    lcur[threadIdx.x] = 0;
  }
  __syncthreads();
#pragma unroll
  for (int it = 0; it < 4; ++it) {
    int d = dreg[it];
    if (d >= 0) {
      int b = d / BUCKET_W;
      int r = atomicAdd(&lcur[b], 1);
      unsigned pack = ((unsigned)(d - b * BUCKET_W) << 17) | (unsigned)sreg[it];
      bucket_buf[(size_t)b * BCAP + lbase[b] + r] = pack;
    }
  }
}

// ---------- pass 2a: bucket -> 50 fine chunks (dense reservation writes) ----------
__global__ __launch_bounds__(256) void k_bin2(const unsigned* __restrict__ bucket_buf,
                                              const int* __restrict__ bucket_cnt,
                                              int* __restrict__ chunk_cur,
                                              unsigned* __restrict__ chunk_buf) {
  const int b   = blockIdx.x / NSEG_P2;
  const int seg = blockIdx.x % NSEG_P2;
  const int n_b = bucket_cnt[b];
  const int s0  = seg * SEG_P2;
  const int s1  = (n_b < s0 + SEG_P2) ? n_b : (s0 + SEG_P2);
  __shared__ int lcnt[50], lbase[50], lcur[50];
  if (threadIdx.x < 50) lcnt[threadIdx.x] = 0;
  __syncthreads();
  unsigned preg[8]; int creg[8];
#pragma unroll
  for (int it = 0; it < 8; ++it) {
    int i = s0 + it * 256 + (int)threadIdx.x;
    unsigned p = 0; int cl = -1;
    if (i < s1) { p = bucket_buf[(size_t)b * BCAP + i]; cl = (int)(p >> 17) / CHUNK_NODES; atomicAdd(&lcnt[cl], 1); }
    preg[it] = p; creg[it] = cl;
  }
  __syncthreads();
  if (threadIdx.x < 50) {
    lbase[threadIdx.x] = atomicAdd(&chunk_cur[b * 50 + threadIdx.x], lcnt[threadIdx.x]);
    lcur[threadIdx.x] = 0;
  }
  __syncthreads();
#pragma unroll
  for (int it = 0; it < 8; ++it) {
    int cl = creg[it];
    if (cl >= 0) {
      unsigned p = preg[it];
      int dl = (int)(p >> 17) - cl * CHUNK_NODES;   // 0..249 within chunk
      int r = atomicAdd(&lcur[cl], 1);
      chunk_buf[(size_t)(b * 50 + cl) * CCAP + lbase[cl] + r] =
          ((unsigned)dl << 17) | (p & 0x1FFFFu);
    }
  }
}

// ---------- exclusive scan of the 400 chunk counts ----------
__global__ __launch_bounds__(512) void k_scan_chunks(const int* __restrict__ chunk_cur,
                                                     int* __restrict__ chunk_base) {
  __shared__ int ls[512];
  const int tid = threadIdx.x;
  int v = (tid < NCHUNK) ? chunk_cur[tid] : 0;
  ls[tid] = v;
  __syncthreads();
  for (int off = 1; off < 512; off <<= 1) {
    int u = (tid >= off) ? ls[tid - off] : 0;
    __syncthreads();
    ls[tid] += u;
    __syncthreads();
  }
  if (tid < NCHUNK) chunk_base[tid] = ls[tid] - v;
}

// ---------- pass 2b: per-chunk LDS counting sort; sequential global writes ----------
__global__ __launch_bounds__(256) void k_sort_chunk(const unsigned* __restrict__ chunk_buf,
                                                    const int* __restrict__ chunk_cur,
                                                    const int* __restrict__ chunk_base,
                                                    int* __restrict__ cnt,
                                                    int* __restrict__ row_start,
                                                    int* __restrict__ sorted_src) {
  const int c    = blockIdx.x;
  const int n_c  = chunk_cur[c];
  const int base = chunk_base[c];
  const unsigned* buf = chunk_buf + (size_t)c * CCAP;
  __shared__ int cntA[256], exclA[256], curA[256];
  __shared__ int sortedL[CCAP];
  const int tid = threadIdx.x;
  cntA[tid] = 0; curA[tid] = 0;
  __syncthreads();
  for (int i = tid; i < n_c; i += 256) atomicAdd(&cntA[buf[i] >> 17], 1);
  __syncthreads();
  int myc = cntA[tid];
  exclA[tid] = myc;
  __syncthreads();
  for (int off = 1; off < 256; off <<= 1) {
    int u = (tid >= off) ? exclA[tid - off] : 0;
    __syncthreads();
    exclA[tid] += u;
    __syncthreads();
  }
  int excl = exclA[tid] - myc;
  if (tid < CHUNK_NODES) {
    int n = c * CHUNK_NODES + tid;
    cnt[n] = myc;
    row_start[n] = base + excl;
  }
  __syncthreads();
  exclA[tid] = excl;
  __syncthreads();
  for (int i = tid; i < n_c; i += 256) {
    unsigned p = buf[i];
    int dl = (int)(p >> 17);
    int pos = exclA[dl] + atomicAdd(&curA[dl], 1);
    sortedL[pos] = (int)(p & 0x1FFFFu);
  }
  __syncthreads();
  for (int i = tid; i < n_c; i += 256) sorted_src[base + i] = sortedL[i];
}

// ---------- dinv = rsqrt(deg+1) ----------
__global__ __launch_bounds__(256) void k_dinv(const int* __restrict__ cnt,
                                              float* __restrict__ dinv) {
  int i = blockIdx.x * 256 + threadIdx.x;
  if (i < N_NODES) dinv[i] = rsqrtf((float)cnt[i] + 1.0f);
}

// ---------- W2t[j][k] = W2[k][j], padded to 64 rows (zero rows j>=47) ----------
__global__ __launch_bounds__(256) void k_prepW2t(const float* __restrict__ W2,
                                                 float* __restrict__ W2t) {
  int i = blockIdx.x * 256 + threadIdx.x;
  if (i >= 64 * 64) return;
  int j = i >> 6, k = i & 63;
  W2t[i] = (j < DIM_C) ? W2[k * DIM_C + j] : 0.f;
}

// ---------- pre-swizzle W1 into per-lane MFMA B-fragment order ----------
__global__ __launch_bounds__(256) void k_prepW1(const float* __restrict__ W1,
                                                short* __restrict__ W1f) {
  int i = blockIdx.x * 256 + threadIdx.x;
  if (i >= 4 * 8 * 64 * 8) return;
  int e    = i & 7;
  int lane = (i >> 3) & 63;
  int ks   = (i >> 9) & 7;
  int wv   = i >> 12;
  int col  = wv * 16 + (lane & 15);
  int k    = ks * 32 + (lane >> 4) * 8 + e;
  W1f[i] = (short)f2bf(W1[k * DIM_H + col]);
}

// ---------- layer 1 GEMM on matrix cores: h1b = bf16(dinv[n] * (x @ W1)) ----------
__global__ __launch_bounds__(256) void k_gemm1(const float* __restrict__ x,
                                               const short* __restrict__ W1f,
                                               const float* __restrict__ dinv,
                                               unsigned short* __restrict__ h1b) {
  __shared__ float xt[64][XPAD];              // 66560B -> 2 blocks/CU
  const int lane = threadIdx.x & 63;
  const int wv   = threadIdx.x >> 6;
  const int m16  = lane & 15;
  const int kb   = lane >> 4;                 // 0..3
  const int base_row = blockIdx.x * 64;

#pragma unroll
  for (int i = 0; i < 16; ++i) {
    int r = i * 4 + wv;                       // wave-uniform row
    int grow = base_row + r;
    if (grow >= N_NODES) grow = N_NODES - 1;
    const float* g = x + (size_t)grow * DIM_IN + lane * 4;
    __builtin_amdgcn_global_load_lds((const __attribute__((address_space(1))) void*)g,
                                     (__attribute__((address_space(3))) void*)&xt[r][0],
                                     16, 0, 0);
  }
  __syncthreads();

  const bf16x8* wf = (const bf16x8*)W1f + (size_t)wv * 8 * 64 + lane;
  f32x4 c0 = {0.f, 0.f, 0.f, 0.f}, c1 = c0, c2 = c0, c3 = c0;
#pragma unroll
  for (int ks = 0; ks < 8; ++ks) {
    bf16x8 bb = wf[ks * 64];
#pragma unroll
    for (int rg = 0; rg < 4; ++rg) {
      const float* xr = &xt[rg * 16 + m16][kb * 8 + ks * 32];
      float4 a0 = *(const float4*)xr;
      float4 a1 = *(const float4*)(xr + 4);
      bf16x8 af;
      af[0] = (short)f2bf(a0.x); af[1] = (short)f2bf(a0.y);
      af[2] = (short)f2bf(a0.z); af[3] = (short)f2bf(a0.w);
      af[4] = (short)f2bf(a1.x); af[5] = (short)f2bf(a1.y);
      af[6] = (short)f2bf(a1.z); af[7] = (short)f2bf(a1.w);
      if (rg == 0) c0 = __builtin_amdgcn_mfma_f32_16x16x32_bf16(af, bb, c0, 0, 0, 0);
      if (rg == 1) c1 = __builtin_amdgcn_mfma_f32_16x16x32_bf16(af, bb, c1, 0, 0, 0);
      if (rg == 2) c2 = __builtin_amdgcn_mfma_f32_16x16x32_bf16(af, bb, c2, 0, 0, 0);
      if (rg == 3) c3 = __builtin_amdgcn_mfma_f32_16x16x32_bf16(af, bb, c3, 0, 0, 0);
    }
  }

  const int j0 = wv * 16 + m16;               // output column
#pragma unroll
  for (int rg = 0; rg < 4; ++rg) {
    f32x4 c = (rg == 0) ? c0 : (rg == 1) ? c1 : (rg == 2) ? c2 : c3;
#pragma unroll
    for (int r = 0; r < 4; ++r) {
      int row = base_row + rg * 16 + kb * 4 + r;
      if (row < N_NODES) h1b[(size_t)row * DIM_H + j0] = f2bf(c[r] * dinv[row]);
    }
  }
}

// ---------- agg1 gather + fused ReLU/pre-scale: h1r = bf16(dinv*relu(h1)) ----------
// Indices pre-loaded coalesced (lane j reads sorted_src[start+j]) and broadcast
// via __shfl -> no per-round index-load latency. h1 = di*sum + b1; h1r = di*relu(h1).
__global__ __launch_bounds__(256) void k_agg1_gather(const unsigned short* __restrict__ h1b,
                                                     const float* __restrict__ dinv,
                                                     const float* __restrict__ b1,
                                                     const int* __restrict__ row_start,
                                                     const int* __restrict__ cnt,
                                                     const int* __restrict__ sorted_src,
                                                     unsigned short* __restrict__ h1r) {
  int n = blockIdx.x * 4 + (threadIdx.x >> 6);
  int j = threadIdx.x & 63;
  if (n >= N_NODES) return;
  int start = row_start[n];
  int deg   = cnt[n];
  int eidx = sorted_src[(deg > 0) ? (start + ((j < deg) ? j : (deg - 1))) : 0];
  float acc0 = bf2f(h1b[(size_t)n * DIM_H + j]);  // self term
  float acc1 = 0.f, acc2 = 0.f, acc3 = 0.f;
  float acc4 = 0.f, acc5 = 0.f, acc6 = 0.f, acc7 = 0.f;
  int k = 0;
  for (; k + 8 <= deg && k + 8 <= 64; k += 8) {
    int s0 = __shfl(eidx, k + 0);
    int s1 = __shfl(eidx, k + 1);
    int s2 = __shfl(eidx, k + 2);
    int s3 = __shfl(eidx, k + 3);
    int s4 = __shfl(eidx, k + 4);
    int s5 = __shfl(eidx, k + 5);
    int s6 = __shfl(eidx, k + 6);
    int s7 = __shfl(eidx, k + 7);
    acc0 += bf2f(h1b[(size_t)s0 * DIM_H + j]);
    acc1 += bf2f(h1b[(size_t)s1 * DIM_H + j]);
    acc2 += bf2f(h1b[(size_t)s2 * DIM_H + j]);
    acc3 += bf2f(h1b[(size_t)s3 * DIM_H + j]);
    acc4 += bf2f(h1b[(size_t)s4 * DIM_H + j]);
    acc5 += bf2f(h1b[(size_t)s5 * DIM_H + j]);
    acc6 += bf2f(h1b[(size_t)s6 * DIM_H + j]);
    acc7 += bf2f(h1b[(size_t)s7 * DIM_H + j]);
  }
  for (; k < deg && k < 64; ++k) {
    int s = __shfl(eidx, k);
    acc0 += bf2f(h1b[(size_t)s * DIM_H + j]);
  }
  for (; k < deg; ++k)   // ultra-rare deg>64 tail
    acc0 += bf2f(h1b[(size_t)sorted_src[start + k] * DIM_H + j]);
  float di = dinv[n];
  float h1 = di * (((acc0 + acc1) + (acc2 + acc3)) + ((acc4 + acc5) + (acc6 + acc7))) + b1[j];
  h1r[(size_t)n * DIM_H + j] = f2bf(di * fmaxf(h1, 0.f));
}

// ---------- agg2 gather + fused W2 matvec + bias + log_softmax ----------
// out[n] = log_softmax( dinv[n] * (sum_g g) @ W2 + b2 ),  g = dinv*relu(h1) rows.
// Gather is 64ch bf16 rows (128B, 2 aligned lines). Matvec: 64 shfl-broadcasts
// of the aggregated channels against lane-local W2t rows (L1-resident, 16KB).
__global__ __launch_bounds__(256) void k_agg2_fused(const unsigned short* __restrict__ h1r,
                                                    const float* __restrict__ dinv,
                                                    const float* __restrict__ W2t,
                                                    const float* __restrict__ b2,
                                                    const int* __restrict__ row_start,
                                                    const int* __restrict__ cnt,
                                                    const int* __restrict__ sorted_src,
                                                    float* __restrict__ out) {
  int n = blockIdx.x * 4 + (threadIdx.x >> 6);
  int j = threadIdx.x & 63;
  if (n >= N_NODES) return;
  int start = row_start[n];
  int deg   = cnt[n];
  int eidx = sorted_src[(deg > 0) ? (start + ((j < deg) ? j : (deg - 1))) : 0];
  float acc0 = bf2f(h1r[(size_t)n * DIM_H + j]);  // self term
  float acc1 = 0.f, acc2 = 0.f, acc3 = 0.f;
  float acc4 = 0.f, acc5 = 0.f, acc6 = 0.f, acc7 = 0.f;
  int k = 0;
  for (; k + 8 <= deg && k + 8 <= 64; k += 8) {
    int s0 = __shfl(eidx, k + 0);
    int s1 = __shfl(eidx, k + 1);
    int s2 = __shfl(eidx, k + 2);
    int s3 = __shfl(eidx, k + 3);
    int s4 = __shfl(eidx, k + 4);
    int s5 = __shfl(eidx, k + 5);
    int s6 = __shfl(eidx, k + 6);
    int s7 = __shfl(eidx, k + 7);
    acc0 += bf2f(h1r[(size_t)s0 * DIM_H + j]);
    acc1 += bf2f(h1r[(size_t)s1 * DIM_H + j]);
    acc2 += bf2f(h1r[(size_t)s2 * DIM_H + j]);
    acc3 += bf2f(h1r[(size_t)s3 * DIM_H + j]);
    acc4 += bf2f(h1r[(size_t)s4 * DIM_H + j]);
    acc5 += bf2f(h1r[(size_t)s5 * DIM_H + j]);
    acc6 += bf2f(h1r[(size_t)s6 * DIM_H + j]);
    acc7 += bf2f(h1r[(size_t)s7 * DIM_H + j]);
  }
  for (; k < deg && k < 64; ++k) {
    int s = __shfl(eidx, k);
    acc0 += bf2f(h1r[(size_t)s * DIM_H + j]);
  }
  for (; k < deg; ++k)
    acc0 += bf2f(h1r[(size_t)sorted_src[start + k] * DIM_H + j]);
  float aggv = ((acc0 + acc1) + (acc2 + acc3)) + ((acc4 + acc5) + (acc6 + acc7));

  // per-node 64x47 matvec: lane j owns output class j (rows j>=47 of W2t are zero)
  const float4* wrow = (const float4*)(W2t + j * 64);
  float y = 0.f;
#pragma unroll
  for (int k4 = 0; k4 < 16; ++k4) {
    float4 w = wrow[k4];
    float a0 = __shfl(aggv, 4 * k4 + 0);
    float a1 = __shfl(aggv, 4 * k4 + 1);
    float a2 = __shfl(aggv, 4 * k4 + 2);
    float a3 = __shfl(aggv, 4 * k4 + 3);
    y = fmaf(a0, w.x, y); y = fmaf(a1, w.y, y);
    y = fmaf(a2, w.z, y); y = fmaf(a3, w.w, y);
  }
  float di = dinv[n];
  float v = (j < DIM_C) ? (di * y + b2[j]) : -INFINITY;

  // fused log_softmax over the 47 classes
  float m = v;
  for (int o = 32; o; o >>= 1) m = fmaxf(m, __shfl_xor(m, o));
  float ex = (j < DIM_C) ? __expf(v - m) : 0.0f;
  float s = ex;
  for (int o = 32; o; o >>= 1) s += __shfl_xor(s, o);
  if (j < DIM_C) out[(size_t)n * DIM_C + j] = v - m - __logf(s);
}

extern "C" void kernel_launch(void* const* d_in, const int* in_sizes, int n_in,
                              void* d_out, int out_size, void* d_ws, size_t ws_size,
                              hipStream_t stream) {
  const float* x  = (const float*)d_in[0];
  const float* W1 = (const float*)d_in[1];
  const float* b1 = (const float*)d_in[2];
  const float* W2 = (const float*)d_in[3];
  const float* b2 = (const float*)d_in[4];
  const int*   ei = (const int*)d_in[5];
  const int* src = ei;
  const int* dst = ei + N_EDGES;
  float* out = (float*)d_out;

  float* ws   = (float*)d_ws;
  float* dinv = ws;                                   // N floats
  float* W2t  = dinv + N_NODES;                       // 64*64 floats (16KB)
  short* W1f  = (short*)(W2t + 64 * 64);              // 16384 shorts (8192 floats)
  unsigned short* h1b = (unsigned short*)(W1f + 16384);      // N*64 bf16 (12.8MB)
  unsigned short* h1r = h1b + (size_t)N_NODES * DIM_H;       // N*64 bf16 (12.8MB)
  unsigned* chunk_buf = (unsigned*)h1b;               // alias: dead before gemm1 writes h1b
  int* ibuf        = (int*)(h1r + (size_t)N_NODES * DIM_H);
  int* cnt         = ibuf;                            // N
  int* row_start   = cnt + N_NODES;                   // N
  int* bucket_cur  = row_start + N_NODES;             // 8 (+pad)
  int* chunk_cur   = bucket_cur + 64;                 // 400
  int* chunk_base  = chunk_cur + NCHUNK;              // 400 (+pad)
  int* sorted_src  = chunk_base + NCHUNK + 64;        // E
  unsigned* bucket_buf = (unsigned*)(sorted_src + N_EDGES);  // NB*BCAP

  const int nblk_n  = (N_NODES + 255) / 256;
  const int nblk_nw = (N_NODES + 3) / 4;              // wave-per-node gathers
  const int nblk_g1 = (N_NODES + 63) / 64;            // 64-row MFMA tiles
  const int nblk_p1 = (N_EDGES + CHUNK_P1 - 1) / CHUNK_P1;   // 1563

  // CSR build: coarse bin -> fine bin -> 400-elem scan -> per-chunk LDS sort
  k_zero<<<1, 512, 0, stream>>>(bucket_cur, chunk_cur);
  k_bin<<<nblk_p1, 256, 0, stream>>>(src, dst, bucket_cur, bucket_buf);
  k_bin2<<<NB * NSEG_P2, 256, 0, stream>>>(bucket_buf, bucket_cur, chunk_cur, chunk_buf);
  k_scan_chunks<<<1, 512, 0, stream>>>(chunk_cur, chunk_base);
  k_sort_chunk<<<NCHUNK, 256, 0, stream>>>(chunk_buf, chunk_cur, chunk_base,
                                           cnt, row_start, sorted_src);
  k_dinv<<<nblk_n, 256, 0, stream>>>(cnt, dinv);
  k_prepW2t<<<16, 256, 0, stream>>>(W2, W2t);
  k_prepW1<<<64, 256, 0, stream>>>(W1, W1f);

  // layer 1 (MFMA, async LDS-staged x, bf16 output)
  k_gemm1<<<nblk_g1, 256, 0, stream>>>(x, W1f, dinv, h1b);
  k_agg1_gather<<<nblk_nw, 256, 0, stream>>>(h1b, dinv, b1, row_start, cnt, sorted_src, h1r);

  // layer 2: gather + fused W2 matvec + bias + log_softmax (gemm2 eliminated)
  k_agg2_fused<<<nblk_nw, 256, 0, stream>>>(h1r, dinv, W2t, b2, row_start, cnt, sorted_src, out);
}

// Round 16
// 251.187 us; speedup vs baseline: 1.2586x; 1.2586x over previous
//
#include <hip/hip_runtime.h>
#include <math.h>

#define N_NODES 100000
#define N_EDGES 1600000
#define DIM_IN  256
#define DIM_H   64
#define DIM_C   47
#define NB       8                            // coarse dst buckets
#define BUCKET_W 12500                        // nodes per bucket
#define BCAP     204000                       // per-bucket capacity (9.5 sigma)
#define CHUNK_P1 1024                         // edges per pass-1 block (4/thread)
#define SEG_P2   2048                         // bucket-buf segment per pass-2a block
#define NSEG_P2  100                          // segments per bucket
#define CHUNK_NODES 250                       // nodes per fine chunk
#define NCHUNK   400                          // N_NODES / 250
#define CCAP     4608                         // per-chunk edge capacity
#define XPAD     260                          // x-tile row stride in floats

typedef __attribute__((ext_vector_type(8))) short bf16x8;
typedef __attribute__((ext_vector_type(4))) float f32x4;

// RNE float -> bf16 bits
static __device__ __forceinline__ unsigned short f2bf(float f) {
  unsigned u = __builtin_bit_cast(unsigned, f);
  u += 0x7FFFu + ((u >> 16) & 1u);
  return (unsigned short)(u >> 16);
}
static __device__ __forceinline__ float bf2f(unsigned short h) {
  unsigned u = ((unsigned)h) << 16;
  return __builtin_bit_cast(float, u);
}

// ---------- zero the counters ----------
__global__ __launch_bounds__(512) void k_zero(int* __restrict__ bucket_cur,
                                              int* __restrict__ chunk_cur) {
  if (threadIdx.x < NB) bucket_cur[threadIdx.x] = 0;
  if (threadIdx.x < NCHUNK) chunk_cur[threadIdx.x] = 0;
}

// ---------- pass 1: coarse octant binning (dense reservation writes) ----------
__global__ __launch_bounds__(256) void k_bin(const int* __restrict__ src,
                                             const int* __restrict__ dst,
                                             int* __restrict__ bucket_cur,
                                             unsigned* __restrict__ bucket_buf) {
  __shared__ int lcnt[NB], lbase[NB], lcur[NB];
  if (threadIdx.x < NB) lcnt[threadIdx.x] = 0;
  __syncthreads();
  const int base = blockIdx.x * CHUNK_P1 + threadIdx.x;
  int dreg[4], sreg[4];
#pragma unroll
  for (int it = 0; it < 4; ++it) {
    int e = base + it * 256;
    int d = -1, s = 0;
    if (e < N_EDGES) { d = dst[e]; s = src[e]; }
    dreg[it] = d; sreg[it] = s;
    if (d >= 0) atomicAdd(&lcnt[d / BUCKET_W], 1);
  }
  __syncthreads();
  if (threadIdx.x < NB) {
    lbase[threadIdx.x] = atomicAdd(&bucket_cur[threadIdx.x], lcnt[threadIdx.x]);
    lcur[threadIdx.x] = 0;
  }
  __syncthreads();
#pragma unroll
  for (int it = 0; it < 4; ++it) {
    int d = dreg[it];
    if (d >= 0) {
      int b = d / BUCKET_W;
      int r = atomicAdd(&lcur[b], 1);
      unsigned pack = ((unsigned)(d - b * BUCKET_W) << 17) | (unsigned)sreg[it];
      bucket_buf[(size_t)b * BCAP + lbase[b] + r] = pack;
    }
  }
}

// ---------- pass 2a: bucket -> 50 fine chunks (dense reservation writes) ----------
__global__ __launch_bounds__(256) void k_bin2(const unsigned* __restrict__ bucket_buf,
                                              const int* __restrict__ bucket_cnt,
                                              int* __restrict__ chunk_cur,
                                              unsigned* __restrict__ chunk_buf) {
  const int b   = blockIdx.x / NSEG_P2;
  const int seg = blockIdx.x % NSEG_P2;
  const int n_b = bucket_cnt[b];
  const int s0  = seg * SEG_P2;
  const int s1  = (n_b < s0 + SEG_P2) ? n_b : (s0 + SEG_P2);
  __shared__ int lcnt[50], lbase[50], lcur[50];
  if (threadIdx.x < 50) lcnt[threadIdx.x] = 0;
  __syncthreads();
  unsigned preg[8]; int creg[8];
#pragma unroll
  for (int it = 0; it < 8; ++it) {
    int i = s0 + it * 256 + (int)threadIdx.x;
    unsigned p = 0; int cl = -1;
    if (i < s1) { p = bucket_buf[(size_t)b * BCAP + i]; cl = (int)(p >> 17) / CHUNK_NODES; atomicAdd(&lcnt[cl], 1); }
    preg[it] = p; creg[it] = cl;
  }
  __syncthreads();
  if (threadIdx.x < 50) {
    lbase[threadIdx.x] = atomicAdd(&chunk_cur[b * 50 + threadIdx.x], lcnt[threadIdx.x]);
    lcur[threadIdx.x] = 0;
  }
  __syncthreads();
#pragma unroll
  for (int it = 0; it < 8; ++it) {
    int cl = creg[it];
    if (cl >= 0) {
      unsigned p = preg[it];
      int dl = (int)(p >> 17) - cl * CHUNK_NODES;   // 0..249 within chunk
      int r = atomicAdd(&lcur[cl], 1);
      chunk_buf[(size_t)(b * 50 + cl) * CCAP + lbase[cl] + r] =
          ((unsigned)dl << 17) | (p & 0x1FFFFu);
    }
  }
}

// ---------- exclusive scan of the 400 chunk counts ----------
__global__ __launch_bounds__(512) void k_scan_chunks(const int* __restrict__ chunk_cur,
                                                     int* __restrict__ chunk_base) {
  __shared__ int ls[512];
  const int tid = threadIdx.x;
  int v = (tid < NCHUNK) ? chunk_cur[tid] : 0;
  ls[tid] = v;
  __syncthreads();
  for (int off = 1; off < 512; off <<= 1) {
    int u = (tid >= off) ? ls[tid - off] : 0;
    __syncthreads();
    ls[tid] += u;
    __syncthreads();
  }
  if (tid < NCHUNK) chunk_base[tid] = ls[tid] - v;
}

// ---------- pass 2b: per-chunk LDS counting sort; sequential global writes ----------
__global__ __launch_bounds__(256) void k_sort_chunk(const unsigned* __restrict__ chunk_buf,
                                                    const int* __restrict__ chunk_cur,
                                                    const int* __restrict__ chunk_base,
                                                    int* __restrict__ cnt,
                                                    int* __restrict__ row_start,
                                                    int* __restrict__ sorted_src) {
  const int c    = blockIdx.x;
  const int n_c  = chunk_cur[c];
  const int base = chunk_base[c];
  const unsigned* buf = chunk_buf + (size_t)c * CCAP;
  __shared__ int cntA[256], exclA[256], curA[256];
  __shared__ int sortedL[CCAP];
  const int tid = threadIdx.x;
  cntA[tid] = 0; curA[tid] = 0;
  __syncthreads();
  for (int i = tid; i < n_c; i += 256) atomicAdd(&cntA[buf[i] >> 17], 1);
  __syncthreads();
  int myc = cntA[tid];
  exclA[tid] = myc;
  __syncthreads();
  for (int off = 1; off < 256; off <<= 1) {
    int u = (tid >= off) ? exclA[tid - off] : 0;
    __syncthreads();
    exclA[tid] += u;
    __syncthreads();
  }
  int excl = exclA[tid] - myc;
  if (tid < CHUNK_NODES) {
    int n = c * CHUNK_NODES + tid;
    cnt[n] = myc;
    row_start[n] = base + excl;
  }
  __syncthreads();
  exclA[tid] = excl;
  __syncthreads();
  for (int i = tid; i < n_c; i += 256) {
    unsigned p = buf[i];
    int dl = (int)(p >> 17);
    int pos = exclA[dl] + atomicAdd(&curA[dl], 1);
    sortedL[pos] = (int)(p & 0x1FFFFu);
  }
  __syncthreads();
  for (int i = tid; i < n_c; i += 256) sorted_src[base + i] = sortedL[i];
}

// ---------- dinv = rsqrt(deg+1) ----------
__global__ __launch_bounds__(256) void k_dinv(const int* __restrict__ cnt,
                                              float* __restrict__ dinv) {
  int i = blockIdx.x * 256 + threadIdx.x;
  if (i < N_NODES) dinv[i] = rsqrtf((float)cnt[i] + 1.0f);
}

// ---------- W2t[j][k] = W2[k][j], padded to 64 rows (zero rows j>=47) ----------
__global__ __launch_bounds__(256) void k_prepW2t(const float* __restrict__ W2,
                                                 float* __restrict__ W2t) {
  int i = blockIdx.x * 256 + threadIdx.x;
  if (i >= 64 * 64) return;
  int j = i >> 6, k = i & 63;
  W2t[i] = (j < DIM_C) ? W2[k * DIM_C + j] : 0.f;
}

// ---------- pre-swizzle W1 into per-lane MFMA B-fragment order ----------
__global__ __launch_bounds__(256) void k_prepW1(const float* __restrict__ W1,
                                                short* __restrict__ W1f) {
  int i = blockIdx.x * 256 + threadIdx.x;
  if (i >= 4 * 8 * 64 * 8) return;
  int e    = i & 7;
  int lane = (i >> 3) & 63;
  int ks   = (i >> 9) & 7;
  int wv   = i >> 12;
  int col  = wv * 16 + (lane & 15);
  int k    = ks * 32 + (lane >> 4) * 8 + e;
  W1f[i] = (short)f2bf(W1[k * DIM_H + col]);
}

// ---------- layer 1 GEMM on matrix cores: h1b = bf16(dinv[n] * (x @ W1)) ----------
__global__ __launch_bounds__(256) void k_gemm1(const float* __restrict__ x,
                                               const short* __restrict__ W1f,
                                               const float* __restrict__ dinv,
                                               unsigned short* __restrict__ h1b) {
  __shared__ float xt[64][XPAD];              // 66560B -> 2 blocks/CU
  const int lane = threadIdx.x & 63;
  const int wv   = threadIdx.x >> 6;
  const int m16  = lane & 15;
  const int kb   = lane >> 4;                 // 0..3
  const int base_row = blockIdx.x * 64;

#pragma unroll
  for (int i = 0; i < 16; ++i) {
    int r = i * 4 + wv;                       // wave-uniform row
    int grow = base_row + r;
    if (grow >= N_NODES) grow = N_NODES - 1;
    const float* g = x + (size_t)grow * DIM_IN + lane * 4;
    __builtin_amdgcn_global_load_lds((const __attribute__((address_space(1))) void*)g,
                                     (__attribute__((address_space(3))) void*)&xt[r][0],
                                     16, 0, 0);
  }
  __syncthreads();

  const bf16x8* wf = (const bf16x8*)W1f + (size_t)wv * 8 * 64 + lane;
  f32x4 c0 = {0.f, 0.f, 0.f, 0.f}, c1 = c0, c2 = c0, c3 = c0;
#pragma unroll
  for (int ks = 0; ks < 8; ++ks) {
    bf16x8 bb = wf[ks * 64];
#pragma unroll
    for (int rg = 0; rg < 4; ++rg) {
      const float* xr = &xt[rg * 16 + m16][kb * 8 + ks * 32];
      float4 a0 = *(const float4*)xr;
      float4 a1 = *(const float4*)(xr + 4);
      bf16x8 af;
      af[0] = (short)f2bf(a0.x); af[1] = (short)f2bf(a0.y);
      af[2] = (short)f2bf(a0.z); af[3] = (short)f2bf(a0.w);
      af[4] = (short)f2bf(a1.x); af[5] = (short)f2bf(a1.y);
      af[6] = (short)f2bf(a1.z); af[7] = (short)f2bf(a1.w);
      if (rg == 0) c0 = __builtin_amdgcn_mfma_f32_16x16x32_bf16(af, bb, c0, 0, 0, 0);
      if (rg == 1) c1 = __builtin_amdgcn_mfma_f32_16x16x32_bf16(af, bb, c1, 0, 0, 0);
      if (rg == 2) c2 = __builtin_amdgcn_mfma_f32_16x16x32_bf16(af, bb, c2, 0, 0, 0);
      if (rg == 3) c3 = __builtin_amdgcn_mfma_f32_16x16x32_bf16(af, bb, c3, 0, 0, 0);
    }
  }

  const int j0 = wv * 16 + m16;               // output column
#pragma unroll
  for (int rg = 0; rg < 4; ++rg) {
    f32x4 c = (rg == 0) ? c0 : (rg == 1) ? c1 : (rg == 2) ? c2 : c3;
#pragma unroll
    for (int r = 0; r < 4; ++r) {
      int row = base_row + rg * 16 + kb * 4 + r;
      if (row < N_NODES) h1b[(size_t)row * DIM_H + j0] = f2bf(c[r] * dinv[row]);
    }
  }
}

// ---------- agg1 gather + fused ReLU/pre-scale: h1r = bf16(dinv*relu(h1)) ----------
// R13-proven direct index loads (R15's shfl-index scheme was part of the regression).
__global__ __launch_bounds__(256) void k_agg1_gather(const unsigned short* __restrict__ h1b,
                                                     const float* __restrict__ dinv,
                                                     const float* __restrict__ b1,
                                                     const int* __restrict__ row_start,
                                                     const int* __restrict__ cnt,
                                                     const int* __restrict__ sorted_src,
                                                     unsigned short* __restrict__ h1r) {
  int n = blockIdx.x * 4 + (threadIdx.x >> 6);
  int j = threadIdx.x & 63;
  if (n >= N_NODES) return;
  int start = row_start[n];
  int deg   = cnt[n];
  float acc0 = bf2f(h1b[(size_t)n * DIM_H + j]);  // self term
  float acc1 = 0.f, acc2 = 0.f, acc3 = 0.f;
  float acc4 = 0.f, acc5 = 0.f, acc6 = 0.f, acc7 = 0.f;
  int k = 0;
  for (; k + 8 <= deg; k += 8) {
    int s0 = sorted_src[start + k + 0];
    int s1 = sorted_src[start + k + 1];
    int s2 = sorted_src[start + k + 2];
    int s3 = sorted_src[start + k + 3];
    int s4 = sorted_src[start + k + 4];
    int s5 = sorted_src[start + k + 5];
    int s6 = sorted_src[start + k + 6];
    int s7 = sorted_src[start + k + 7];
    acc0 += bf2f(h1b[(size_t)s0 * DIM_H + j]);
    acc1 += bf2f(h1b[(size_t)s1 * DIM_H + j]);
    acc2 += bf2f(h1b[(size_t)s2 * DIM_H + j]);
    acc3 += bf2f(h1b[(size_t)s3 * DIM_H + j]);
    acc4 += bf2f(h1b[(size_t)s4 * DIM_H + j]);
    acc5 += bf2f(h1b[(size_t)s5 * DIM_H + j]);
    acc6 += bf2f(h1b[(size_t)s6 * DIM_H + j]);
    acc7 += bf2f(h1b[(size_t)s7 * DIM_H + j]);
  }
  for (; k + 2 <= deg; k += 2) {
    int s0 = sorted_src[start + k + 0];
    int s1 = sorted_src[start + k + 1];
    acc0 += bf2f(h1b[(size_t)s0 * DIM_H + j]);
    acc1 += bf2f(h1b[(size_t)s1 * DIM_H + j]);
  }
  for (; k < deg; ++k)
    acc0 += bf2f(h1b[(size_t)sorted_src[start + k] * DIM_H + j]);
  float di = dinv[n];
  float h1 = di * (((acc0 + acc1) + (acc2 + acc3)) + ((acc4 + acc5) + (acc6 + acc7))) + b1[j];
  h1r[(size_t)n * DIM_H + j] = f2bf(di * fmaxf(h1, 0.f));
}

// ---------- agg2 gather + fused W2 matvec + bias + log_softmax ----------
// W2t staged in LDS (padded rows: conflict-free, immune to the L1 thrash that
// sank R15: gather stream evicted W2t from L1 -> 16KB L2 refetch per node).
// aggv staged per-wave in LDS; matvec reads are row-local + broadcast.
__global__ __launch_bounds__(256) void k_agg2_fused(const unsigned short* __restrict__ h1r,
                                                    const float* __restrict__ dinv,
                                                    const float* __restrict__ W2t,
                                                    const float* __restrict__ b2,
                                                    const int* __restrict__ row_start,
                                                    const int* __restrict__ cnt,
                                                    const int* __restrict__ sorted_src,
                                                    float* __restrict__ out) {
  __shared__ float W2l[64][65];               // padded: lane j row -> bank (j+..)%32
  __shared__ float av[4][64];                 // per-wave aggv staging (broadcast reads)
  for (int i = threadIdx.x; i < 64 * 64; i += 256) {
    W2l[i >> 6][i & 63] = W2t[i];
  }
  __syncthreads();

  int n = blockIdx.x * 4 + (threadIdx.x >> 6);  // grid is exact: 25000*4 == N_NODES
  int j = threadIdx.x & 63;
  int wv = threadIdx.x >> 6;
  int start = row_start[n];
  int deg   = cnt[n];
  float acc0 = bf2f(h1r[(size_t)n * DIM_H + j]);  // self term
  float acc1 = 0.f, acc2 = 0.f, acc3 = 0.f;
  float acc4 = 0.f, acc5 = 0.f, acc6 = 0.f, acc7 = 0.f;
  int k = 0;
  for (; k + 8 <= deg; k += 8) {
    int s0 = sorted_src[start + k + 0];
    int s1 = sorted_src[start + k + 1];
    int s2 = sorted_src[start + k + 2];
    int s3 = sorted_src[start + k + 3];
    int s4 = sorted_src[start + k + 4];
    int s5 = sorted_src[start + k + 5];
    int s6 = sorted_src[start + k + 6];
    int s7 = sorted_src[start + k + 7];
    acc0 += bf2f(h1r[(size_t)s0 * DIM_H + j]);
    acc1 += bf2f(h1r[(size_t)s1 * DIM_H + j]);
    acc2 += bf2f(h1r[(size_t)s2 * DIM_H + j]);
    acc3 += bf2f(h1r[(size_t)s3 * DIM_H + j]);
    acc4 += bf2f(h1r[(size_t)s4 * DIM_H + j]);
    acc5 += bf2f(h1r[(size_t)s5 * DIM_H + j]);
    acc6 += bf2f(h1r[(size_t)s6 * DIM_H + j]);
    acc7 += bf2f(h1r[(size_t)s7 * DIM_H + j]);
  }
  for (; k + 2 <= deg; k += 2) {
    int s0 = sorted_src[start + k + 0];
    int s1 = sorted_src[start + k + 1];
    acc0 += bf2f(h1r[(size_t)s0 * DIM_H + j]);
    acc1 += bf2f(h1r[(size_t)s1 * DIM_H + j]);
  }
  for (; k < deg; ++k)
    acc0 += bf2f(h1r[(size_t)sorted_src[start + k] * DIM_H + j]);
  float aggv = ((acc0 + acc1) + (acc2 + acc3)) + ((acc4 + acc5) + (acc6 + acc7));

  // per-node 64x47 matvec via LDS (wave-synchronous: DS ops of a wave are ordered)
  av[wv][j] = aggv;
  float y0 = 0.f, y1 = 0.f, y2 = 0.f, y3 = 0.f;
#pragma unroll
  for (int k4 = 0; k4 < 16; ++k4) {
    float4 w = *(const float4*)&W2l[j][4 * k4];
    float4 a = *(const float4*)&av[wv][4 * k4];   // same addr across lanes -> broadcast
    y0 = fmaf(a.x, w.x, y0);
    y1 = fmaf(a.y, w.y, y1);
    y2 = fmaf(a.z, w.z, y2);
    y3 = fmaf(a.w, w.w, y3);
  }
  float y = (y0 + y1) + (y2 + y3);
  float di = dinv[n];
  float v = (j < DIM_C) ? (di * y + b2[j]) : -INFINITY;

  // fused log_softmax over the 47 classes
  float m = v;
  for (int o = 32; o; o >>= 1) m = fmaxf(m, __shfl_xor(m, o));
  float ex = (j < DIM_C) ? __expf(v - m) : 0.0f;
  float s = ex;
  for (int o = 32; o; o >>= 1) s += __shfl_xor(s, o);
  if (j < DIM_C) out[(size_t)n * DIM_C + j] = v - m - __logf(s);
}

extern "C" void kernel_launch(void* const* d_in, const int* in_sizes, int n_in,
                              void* d_out, int out_size, void* d_ws, size_t ws_size,
                              hipStream_t stream) {
  const float* x  = (const float*)d_in[0];
  const float* W1 = (const float*)d_in[1];
  const float* b1 = (const float*)d_in[2];
  const float* W2 = (const float*)d_in[3];
  const float* b2 = (const float*)d_in[4];
  const int*   ei = (const int*)d_in[5];
  const int* src = ei;
  const int* dst = ei + N_EDGES;
  float* out = (float*)d_out;

  float* ws   = (float*)d_ws;
  float* dinv = ws;                                   // N floats
  float* W2t  = dinv + N_NODES;                       // 64*64 floats (16KB)
  short* W1f  = (short*)(W2t + 64 * 64);              // 16384 shorts
  unsigned short* h1b = (unsigned short*)(W1f + 16384);      // N*64 bf16 (12.8MB)
  unsigned short* h1r = h1b + (size_t)N_NODES * DIM_H;       // N*64 bf16 (12.8MB)
  unsigned* chunk_buf = (unsigned*)h1b;               // alias: dead before gemm1 writes h1b
  int* ibuf        = (int*)(h1r + (size_t)N_NODES * DIM_H);
  int* cnt         = ibuf;                            // N
  int* row_start   = cnt + N_NODES;                   // N
  int* bucket_cur  = row_start + N_NODES;             // 8 (+pad)
  int* chunk_cur   = bucket_cur + 64;                 // 400
  int* chunk_base  = chunk_cur + NCHUNK;              // 400 (+pad)
  int* sorted_src  = chunk_base + NCHUNK + 64;        // E
  unsigned* bucket_buf = (unsigned*)(sorted_src + N_EDGES);  // NB*BCAP

  const int nblk_n  = (N_NODES + 255) / 256;
  const int nblk_nw = (N_NODES + 3) / 4;              // wave-per-node gathers
  const int nblk_g1 = (N_NODES + 63) / 64;            // 64-row MFMA tiles
  const int nblk_p1 = (N_EDGES + CHUNK_P1 - 1) / CHUNK_P1;   // 1563

  // CSR build: coarse bin -> fine bin -> 400-elem scan -> per-chunk LDS sort
  k_zero<<<1, 512, 0, stream>>>(bucket_cur, chunk_cur);
  k_bin<<<nblk_p1, 256, 0, stream>>>(src, dst, bucket_cur, bucket_buf);
  k_bin2<<<NB * NSEG_P2, 256, 0, stream>>>(bucket_buf, bucket_cur, chunk_cur, chunk_buf);
  k_scan_chunks<<<1, 512, 0, stream>>>(chunk_cur, chunk_base);
  k_sort_chunk<<<NCHUNK, 256, 0, stream>>>(chunk_buf, chunk_cur, chunk_base,
                                           cnt, row_start, sorted_src);
  k_dinv<<<nblk_n, 256, 0, stream>>>(cnt, dinv);
  k_prepW2t<<<16, 256, 0, stream>>>(W2, W2t);
  k_prepW1<<<64, 256, 0, stream>>>(W1, W1f);

  // layer 1 (MFMA, async LDS-staged x, bf16 output)
  k_gemm1<<<nblk_g1, 256, 0, stream>>>(x, W1f, dinv, h1b);
  k_agg1_gather<<<nblk_nw, 256, 0, stream>>>(h1b, dinv, b1, row_start, cnt, sorted_src, h1r);

  // layer 2: gather + fused W2 matvec (LDS) + bias + log_softmax
  k_agg2_fused<<<nblk_nw, 256, 0, stream>>>(h1r, dinv, W2t, b2, row_start, cnt, sorted_src, out);
}

// Round 17
// 236.258 us; speedup vs baseline: 1.3381x; 1.0632x over previous
//
#include <hip/hip_runtime.h>
#include <math.h>

#define N_NODES 100000
#define N_EDGES 1600000
#define DIM_IN  256
#define DIM_H   64
#define DIM_C   47
#define DIM_CP  48                            // padded h2 row stride (96B bf16)
#define NB       8                            // coarse dst buckets
#define BUCKET_W 12500                        // nodes per bucket
#define BCAP     204000                       // per-bucket capacity (9.5 sigma)
#define CHUNK_P1 1024                         // edges per pass-1 block (4/thread)
#define SEG_P2   2048                         // bucket-buf segment per pass-2a block
#define NSEG_P2  100                          // segments per bucket
#define CHUNK_NODES 250                       // nodes per fine chunk
#define NCHUNK   400                          // N_NODES / 250
#define CCAP     4608                         // per-chunk edge capacity
#define XBP      264                          // bf16 x-tile row stride (+8 -> 4-bank rotate)

typedef __attribute__((ext_vector_type(8))) short bf16x8;
typedef __attribute__((ext_vector_type(4))) float f32x4;

// RNE float -> bf16 bits
static __device__ __forceinline__ unsigned short f2bf(float f) {
  unsigned u = __builtin_bit_cast(unsigned, f);
  u += 0x7FFFu + ((u >> 16) & 1u);
  return (unsigned short)(u >> 16);
}
static __device__ __forceinline__ float bf2f(unsigned short h) {
  unsigned u = ((unsigned)h) << 16;
  return __builtin_bit_cast(float, u);
}

// ---------- zero the counters ----------
__global__ __launch_bounds__(512) void k_zero(int* __restrict__ bucket_cur,
                                              int* __restrict__ chunk_cur) {
  if (threadIdx.x < NB) bucket_cur[threadIdx.x] = 0;
  if (threadIdx.x < NCHUNK) chunk_cur[threadIdx.x] = 0;
}

// ---------- pass 1: coarse octant binning (dense reservation writes) ----------
__global__ __launch_bounds__(256) void k_bin(const int* __restrict__ src,
                                             const int* __restrict__ dst,
                                             int* __restrict__ bucket_cur,
                                             unsigned* __restrict__ bucket_buf) {
  __shared__ int lcnt[NB], lbase[NB], lcur[NB];
  if (threadIdx.x < NB) lcnt[threadIdx.x] = 0;
  __syncthreads();
  const int base = blockIdx.x * CHUNK_P1 + threadIdx.x;
  int dreg[4], sreg[4];
#pragma unroll
  for (int it = 0; it < 4; ++it) {
    int e = base + it * 256;
    int d = -1, s = 0;
    if (e < N_EDGES) { d = dst[e]; s = src[e]; }
    dreg[it] = d; sreg[it] = s;
    if (d >= 0) atomicAdd(&lcnt[d / BUCKET_W], 1);
  }
  __syncthreads();
  if (threadIdx.x < NB) {
    lbase[threadIdx.x] = atomicAdd(&bucket_cur[threadIdx.x], lcnt[threadIdx.x]);
    lcur[threadIdx.x] = 0;
  }
  __syncthreads();
#pragma unroll
  for (int it = 0; it < 4; ++it) {
    int d = dreg[it];
    if (d >= 0) {
      int b = d / BUCKET_W;
      int r = atomicAdd(&lcur[b], 1);
      unsigned pack = ((unsigned)(d - b * BUCKET_W) << 17) | (unsigned)sreg[it];
      bucket_buf[(size_t)b * BCAP + lbase[b] + r] = pack;
    }
  }
}

// ---------- pass 2a: bucket -> 50 fine chunks (dense reservation writes) ----------
__global__ __launch_bounds__(256) void k_bin2(const unsigned* __restrict__ bucket_buf,
                                              const int* __restrict__ bucket_cnt,
                                              int* __restrict__ chunk_cur,
                                              unsigned* __restrict__ chunk_buf) {
  const int b   = blockIdx.x / NSEG_P2;
  const int seg = blockIdx.x % NSEG_P2;
  const int n_b = bucket_cnt[b];
  const int s0  = seg * SEG_P2;
  const int s1  = (n_b < s0 + SEG_P2) ? n_b : (s0 + SEG_P2);
  __shared__ int lcnt[50], lbase[50], lcur[50];
  if (threadIdx.x < 50) lcnt[threadIdx.x] = 0;
  __syncthreads();
  unsigned preg[8]; int creg[8];
#pragma unroll
  for (int it = 0; it < 8; ++it) {
    int i = s0 + it * 256 + (int)threadIdx.x;
    unsigned p = 0; int cl = -1;
    if (i < s1) { p = bucket_buf[(size_t)b * BCAP + i]; cl = (int)(p >> 17) / CHUNK_NODES; atomicAdd(&lcnt[cl], 1); }
    preg[it] = p; creg[it] = cl;
  }
  __syncthreads();
  if (threadIdx.x < 50) {
    lbase[threadIdx.x] = atomicAdd(&chunk_cur[b * 50 + threadIdx.x], lcnt[threadIdx.x]);
    lcur[threadIdx.x] = 0;
  }
  __syncthreads();
#pragma unroll
  for (int it = 0; it < 8; ++it) {
    int cl = creg[it];
    if (cl >= 0) {
      unsigned p = preg[it];
      int dl = (int)(p >> 17) - cl * CHUNK_NODES;   // 0..249 within chunk
      int r = atomicAdd(&lcur[cl], 1);
      chunk_buf[(size_t)(b * 50 + cl) * CCAP + lbase[cl] + r] =
          ((unsigned)dl << 17) | (p & 0x1FFFFu);
    }
  }
}

// ---------- exclusive scan of the 400 chunk counts ----------
__global__ __launch_bounds__(512) void k_scan_chunks(const int* __restrict__ chunk_cur,
                                                     int* __restrict__ chunk_base) {
  __shared__ int ls[512];
  const int tid = threadIdx.x;
  int v = (tid < NCHUNK) ? chunk_cur[tid] : 0;
  ls[tid] = v;
  __syncthreads();
  for (int off = 1; off < 512; off <<= 1) {
    int u = (tid >= off) ? ls[tid - off] : 0;
    __syncthreads();
    ls[tid] += u;
    __syncthreads();
  }
  if (tid < NCHUNK) chunk_base[tid] = ls[tid] - v;
}

// ---------- pass 2b: per-chunk LDS counting sort; sequential global writes ----------
__global__ __launch_bounds__(256) void k_sort_chunk(const unsigned* __restrict__ chunk_buf,
                                                    const int* __restrict__ chunk_cur,
                                                    const int* __restrict__ chunk_base,
                                                    int* __restrict__ cnt,
                                                    int* __restrict__ row_start,
                                                    int* __restrict__ sorted_src) {
  const int c    = blockIdx.x;
  const int n_c  = chunk_cur[c];
  const int base = chunk_base[c];
  const unsigned* buf = chunk_buf + (size_t)c * CCAP;
  __shared__ int cntA[256], exclA[256], curA[256];
  __shared__ int sortedL[CCAP];
  const int tid = threadIdx.x;
  cntA[tid] = 0; curA[tid] = 0;
  __syncthreads();
  for (int i = tid; i < n_c; i += 256) atomicAdd(&cntA[buf[i] >> 17], 1);
  __syncthreads();
  int myc = cntA[tid];
  exclA[tid] = myc;
  __syncthreads();
  for (int off = 1; off < 256; off <<= 1) {
    int u = (tid >= off) ? exclA[tid - off] : 0;
    __syncthreads();
    exclA[tid] += u;
    __syncthreads();
  }
  int excl = exclA[tid] - myc;
  if (tid < CHUNK_NODES) {
    int n = c * CHUNK_NODES + tid;
    cnt[n] = myc;
    row_start[n] = base + excl;
  }
  __syncthreads();
  exclA[tid] = excl;
  __syncthreads();
  for (int i = tid; i < n_c; i += 256) {
    unsigned p = buf[i];
    int dl = (int)(p >> 17);
    int pos = exclA[dl] + atomicAdd(&curA[dl], 1);
    sortedL[pos] = (int)(p & 0x1FFFFu);
  }
  __syncthreads();
  for (int i = tid; i < n_c; i += 256) sorted_src[base + i] = sortedL[i];
}

// ---------- dinv = rsqrt(deg+1) ----------
__global__ __launch_bounds__(256) void k_dinv(const int* __restrict__ cnt,
                                              float* __restrict__ dinv) {
  int i = blockIdx.x * 256 + threadIdx.x;
  if (i < N_NODES) dinv[i] = rsqrtf((float)cnt[i] + 1.0f);
}

// ---------- pad W2 (64x47) into W2p (64x48) ----------
__global__ __launch_bounds__(256) void k_padW2(const float* __restrict__ W2,
                                               float* __restrict__ W2p) {
  int i = blockIdx.x * 256 + threadIdx.x;
  if (i >= DIM_H * DIM_CP) return;
  int k = i / DIM_CP, j = i % DIM_CP;
  W2p[i] = (j < DIM_C) ? W2[k * DIM_C + j] : 0.f;
}

// ---------- pre-swizzle W1 into per-lane MFMA B-fragment order ----------
__global__ __launch_bounds__(256) void k_prepW1(const float* __restrict__ W1,
                                                short* __restrict__ W1f) {
  int i = blockIdx.x * 256 + threadIdx.x;
  if (i >= 4 * 8 * 64 * 8) return;
  int e    = i & 7;
  int lane = (i >> 3) & 63;
  int ks   = (i >> 9) & 7;
  int wv   = i >> 12;
  int col  = wv * 16 + (lane & 15);
  int k    = ks * 32 + (lane >> 4) * 8 + e;
  W1f[i] = (short)f2bf(W1[k * DIM_H + col]);
}

// ---------- layer 1 GEMM on matrix cores: h1b = bf16(dinv[n] * (x @ W1)) ----------
// One-pass cooperative f32->bf16 conversion into a bf16 LDS tile (33.8KB -> 4
// blocks/CU), then 1 ds_read_b128 per MFMA with ZERO per-MFMA conversion ops.
// (R13-R16 versions converted each element 4x redundantly: ~75cy staging per
// 5cy MFMA, VALU-bound.)
__global__ __launch_bounds__(256) void k_gemm1(const float* __restrict__ x,
                                               const short* __restrict__ W1f,
                                               const float* __restrict__ dinv,
                                               unsigned short* __restrict__ h1b) {
  __shared__ unsigned short xb[64][XBP];      // 33792B
  const int lane = threadIdx.x & 63;
  const int wv   = threadIdx.x >> 6;
  const int m16  = lane & 15;
  const int kb   = lane >> 4;                 // 0..3
  const int base_row = blockIdx.x * 64;

  // stage: 4 rows per iteration, coalesced float4 loads, convert once, b64 write
#pragma unroll 4
  for (int i = 0; i < 16; ++i) {
    int r = i * 4 + wv;
    int grow = base_row + r;
    if (grow >= N_NODES) grow = N_NODES - 1;  // tail: duplicate row, stores guarded
    float4 v = *(const float4*)(x + (size_t)grow * DIM_IN + lane * 4);
    ushort4 b;
    b.x = f2bf(v.x); b.y = f2bf(v.y); b.z = f2bf(v.z); b.w = f2bf(v.w);
    *(ushort4*)&xb[r][lane * 4] = b;
  }
  __syncthreads();

  const bf16x8* wf = (const bf16x8*)W1f + (size_t)wv * 8 * 64 + lane;
  f32x4 c0 = {0.f, 0.f, 0.f, 0.f}, c1 = c0, c2 = c0, c3 = c0;
#pragma unroll
  for (int ks = 0; ks < 8; ++ks) {
    bf16x8 bb = wf[ks * 64];
#pragma unroll
    for (int rg = 0; rg < 4; ++rg) {
      bf16x8 af = *(const bf16x8*)&xb[rg * 16 + m16][ks * 32 + kb * 8];
      if (rg == 0) c0 = __builtin_amdgcn_mfma_f32_16x16x32_bf16(af, bb, c0, 0, 0, 0);
      if (rg == 1) c1 = __builtin_amdgcn_mfma_f32_16x16x32_bf16(af, bb, c1, 0, 0, 0);
      if (rg == 2) c2 = __builtin_amdgcn_mfma_f32_16x16x32_bf16(af, bb, c2, 0, 0, 0);
      if (rg == 3) c3 = __builtin_amdgcn_mfma_f32_16x16x32_bf16(af, bb, c3, 0, 0, 0);
    }
  }

  const int j0 = wv * 16 + m16;               // output column
#pragma unroll
  for (int rg = 0; rg < 4; ++rg) {
    f32x4 c = (rg == 0) ? c0 : (rg == 1) ? c1 : (rg == 2) ? c2 : c3;
#pragma unroll
    for (int r = 0; r < 4; ++r) {
      int row = base_row + rg * 16 + kb * 4 + r;
      if (row < N_NODES) h1b[(size_t)row * DIM_H + j0] = f2bf(c[r] * dinv[row]);
    }
  }
}

// ---------- agg1 gather: wave per node, lane = channel, bf16 table ----------
__global__ __launch_bounds__(256) void k_agg1_gather(const unsigned short* __restrict__ h1b,
                                                     const float* __restrict__ dinv,
                                                     const float* __restrict__ b1,
                                                     const int* __restrict__ row_start,
                                                     const int* __restrict__ cnt,
                                                     const int* __restrict__ sorted_src,
                                                     float* __restrict__ agg1) {
  int n = blockIdx.x * 4 + (threadIdx.x >> 6);
  int j = threadIdx.x & 63;
  if (n >= N_NODES) return;
  int start = row_start[n];
  int deg   = cnt[n];
  float acc0 = bf2f(h1b[(size_t)n * DIM_H + j]);  // self term
  float acc1 = 0.f, acc2 = 0.f, acc3 = 0.f;
  float acc4 = 0.f, acc5 = 0.f, acc6 = 0.f, acc7 = 0.f;
  int k = 0;
  for (; k + 8 <= deg; k += 8) {
    int s0 = sorted_src[start + k + 0];
    int s1 = sorted_src[start + k + 1];
    int s2 = sorted_src[start + k + 2];
    int s3 = sorted_src[start + k + 3];
    int s4 = sorted_src[start + k + 4];
    int s5 = sorted_src[start + k + 5];
    int s6 = sorted_src[start + k + 6];
    int s7 = sorted_src[start + k + 7];
    acc0 += bf2f(h1b[(size_t)s0 * DIM_H + j]);
    acc1 += bf2f(h1b[(size_t)s1 * DIM_H + j]);
    acc2 += bf2f(h1b[(size_t)s2 * DIM_H + j]);
    acc3 += bf2f(h1b[(size_t)s3 * DIM_H + j]);
    acc4 += bf2f(h1b[(size_t)s4 * DIM_H + j]);
    acc5 += bf2f(h1b[(size_t)s5 * DIM_H + j]);
    acc6 += bf2f(h1b[(size_t)s6 * DIM_H + j]);
    acc7 += bf2f(h1b[(size_t)s7 * DIM_H + j]);
  }
  for (; k + 2 <= deg; k += 2) {
    int s0 = sorted_src[start + k + 0];
    int s1 = sorted_src[start + k + 1];
    acc0 += bf2f(h1b[(size_t)s0 * DIM_H + j]);
    acc1 += bf2f(h1b[(size_t)s1 * DIM_H + j]);
  }
  for (; k < deg; ++k)
    acc0 += bf2f(h1b[(size_t)sorted_src[start + k] * DIM_H + j]);
  float di = dinv[n];
  agg1[(size_t)n * DIM_H + j] =
      di * (((acc0 + acc1) + (acc2 + acc3)) + ((acc4 + acc5) + (acc6 + acc7))) + b1[j];
}

// ---------- layer 2 GEMM + ReLU + dinv pre-scale -> bf16 h2b ----------
__global__ __launch_bounds__(192) void k_gemm2(const float* __restrict__ agg1,
                                               const float* __restrict__ W2p,
                                               const float* __restrict__ dinv,
                                               unsigned short* __restrict__ h2b) {
  const int lane = threadIdx.x & 63;
  const int j0   = __builtin_amdgcn_readfirstlane((threadIdx.x >> 6) * 16);
  int row = blockIdx.x * 64 + lane;
  if (row >= N_NODES) row = N_NODES - 1;
  const float4* xr = (const float4*)(agg1 + (size_t)row * DIM_H);

  float4 xv[16];
#pragma unroll
  for (int k4 = 0; k4 < 16; ++k4) xv[k4] = xr[k4];
  __builtin_amdgcn_sched_barrier(0);

  float acc[16];
#pragma unroll
  for (int j = 0; j < 16; ++j) acc[j] = 0.f;

#pragma unroll
  for (int k4 = 0; k4 < DIM_H / 4; ++k4) {
    float4 v = xv[k4];
    v.x = fmaxf(v.x, 0.f); v.y = fmaxf(v.y, 0.f);
    v.z = fmaxf(v.z, 0.f); v.w = fmaxf(v.w, 0.f);
#pragma unroll
    for (int kk = 0; kk < 4; ++kk) {
      float xk = (kk == 0) ? v.x : (kk == 1) ? v.y : (kk == 2) ? v.z : v.w;
      const float* wrow = W2p + (size_t)(4 * k4 + kk) * DIM_CP + j0;  // uniform -> s_load
#pragma unroll
      for (int j = 0; j < 16; ++j)
        acc[j] = fmaf(xk, wrow[j], acc[j]);
    }
  }

  float di = dinv[row];
  unsigned* outp = (unsigned*)(h2b + (size_t)row * DIM_CP + j0);
#pragma unroll
  for (int p = 0; p < 8; ++p) {
    unsigned lo = f2bf(di * acc[2 * p]);
    unsigned hi = f2bf(di * acc[2 * p + 1]);
    outp[p] = lo | (hi << 16);
  }
}

// ---------- agg2 gather + fused log_softmax: bf16 table, wave per node ----------
__global__ __launch_bounds__(256) void k_agg2_gather(const unsigned short* __restrict__ h2b,
                                                     const float* __restrict__ dinv,
                                                     const float* __restrict__ b2,
                                                     const int* __restrict__ row_start,
                                                     const int* __restrict__ cnt,
                                                     const int* __restrict__ sorted_src,
                                                     float* __restrict__ out) {
  int n = blockIdx.x * 4 + (threadIdx.x >> 6);
  int j = threadIdx.x & 63;
  if (n >= N_NODES) return;
  int jj = (j < DIM_C) ? j : DIM_C;  // lanes >=47 read the zero pad
  int start = row_start[n];
  int deg   = cnt[n];
  float acc0 = bf2f(h2b[(size_t)n * DIM_CP + jj]);  // self term
  float acc1 = 0.f, acc2 = 0.f, acc3 = 0.f;
  float acc4 = 0.f, acc5 = 0.f, acc6 = 0.f, acc7 = 0.f;
  int k = 0;
  for (; k + 8 <= deg; k += 8) {
    int s0 = sorted_src[start + k + 0];
    int s1 = sorted_src[start + k + 1];
    int s2 = sorted_src[start + k + 2];
    int s3 = sorted_src[start + k + 3];
    int s4 = sorted_src[start + k + 4];
    int s5 = sorted_src[start + k + 5];
    int s6 = sorted_src[start + k + 6];
    int s7 = sorted_src[start + k + 7];
    acc0 += bf2f(h2b[(size_t)s0 * DIM_CP + jj]);
    acc1 += bf2f(h2b[(size_t)s1 * DIM_CP + jj]);
    acc2 += bf2f(h2b[(size_t)s2 * DIM_CP + jj]);
    acc3 += bf2f(h2b[(size_t)s3 * DIM_CP + jj]);
    acc4 += bf2f(h2b[(size_t)s4 * DIM_CP + jj]);
    acc5 += bf2f(h2b[(size_t)s5 * DIM_CP + jj]);
    acc6 += bf2f(h2b[(size_t)s6 * DIM_CP + jj]);
    acc7 += bf2f(h2b[(size_t)s7 * DIM_CP + jj]);
  }
  for (; k + 2 <= deg; k += 2) {
    int s0 = sorted_src[start + k + 0];
    int s1 = sorted_src[start + k + 1];
    acc0 += bf2f(h2b[(size_t)s0 * DIM_CP + jj]);
    acc1 += bf2f(h2b[(size_t)s1 * DIM_CP + jj]);
  }
  for (; k < deg; ++k)
    acc0 += bf2f(h2b[(size_t)sorted_src[start + k] * DIM_CP + jj]);
  float di = dinv[n];
  float acc = di * (((acc0 + acc1) + (acc2 + acc3)) + ((acc4 + acc5) + (acc6 + acc7)))
            + ((j < DIM_C) ? b2[jj] : 0.f);

  // fused log_softmax over the 47 classes
  float v = (j < DIM_C) ? acc : -INFINITY;
  float m = v;
  for (int o = 32; o; o >>= 1) m = fmaxf(m, __shfl_xor(m, o));
  float ex = (j < DIM_C) ? __expf(v - m) : 0.0f;
  float s = ex;
  for (int o = 32; o; o >>= 1) s += __shfl_xor(s, o);
  if (j < DIM_C) out[(size_t)n * DIM_C + j] = v - m - __logf(s);
}

extern "C" void kernel_launch(void* const* d_in, const int* in_sizes, int n_in,
                              void* d_out, int out_size, void* d_ws, size_t ws_size,
                              hipStream_t stream) {
  const float* x  = (const float*)d_in[0];
  const float* W1 = (const float*)d_in[1];
  const float* b1 = (const float*)d_in[2];
  const float* W2 = (const float*)d_in[3];
  const float* b2 = (const float*)d_in[4];
  const int*   ei = (const int*)d_in[5];
  const int* src = ei;
  const int* dst = ei + N_EDGES;
  float* out = (float*)d_out;

  float* ws   = (float*)d_ws;
  float* dinv = ws;                                   // N floats
  float* W2p  = dinv + N_NODES;                       // 64*48 floats
  short* W1f  = (short*)(W2p + DIM_H * DIM_CP);       // 16384 shorts
  unsigned short* h1b = (unsigned short*)(W1f + 16384);      // N*64 bf16 (12.8MB)
  float* agg1 = (float*)(h1b + (size_t)N_NODES * DIM_H);     // N*64 f32 (25.6MB)
  unsigned short* h2b = h1b;                          // alias: h1b dead after agg1_gather
  unsigned* chunk_buf = (unsigned*)h1b;               // alias: dead before gemm1 writes h1b
  int* ibuf        = (int*)(agg1 + (size_t)N_NODES * DIM_H);
  int* cnt         = ibuf;                            // N
  int* row_start   = cnt + N_NODES;                   // N
  int* bucket_cur  = row_start + N_NODES;             // 8 (+pad)
  int* chunk_cur   = bucket_cur + 64;                 // 400
  int* chunk_base  = chunk_cur + NCHUNK;              // 400 (+pad)
  int* sorted_src  = chunk_base + NCHUNK + 64;        // E
  unsigned* bucket_buf = (unsigned*)(sorted_src + N_EDGES);  // NB*BCAP

  const int nblk_n  = (N_NODES + 255) / 256;
  const int nblk_nw = (N_NODES + 3) / 4;              // wave-per-node gathers
  const int nblk_g1 = (N_NODES + 63) / 64;            // 64-row MFMA tiles
  const int nblk_g2 = (N_NODES + 63) / 64;            // fp32 gemm2 tiles
  const int nblk_p1 = (N_EDGES + CHUNK_P1 - 1) / CHUNK_P1;   // 1563

  // CSR build: coarse bin -> fine bin -> 400-elem scan -> per-chunk LDS sort
  k_zero<<<1, 512, 0, stream>>>(bucket_cur, chunk_cur);
  k_bin<<<nblk_p1, 256, 0, stream>>>(src, dst, bucket_cur, bucket_buf);
  k_bin2<<<NB * NSEG_P2, 256, 0, stream>>>(bucket_buf, bucket_cur, chunk_cur, chunk_buf);
  k_scan_chunks<<<1, 512, 0, stream>>>(chunk_cur, chunk_base);
  k_sort_chunk<<<NCHUNK, 256, 0, stream>>>(chunk_buf, chunk_cur, chunk_base,
                                           cnt, row_start, sorted_src);
  k_dinv<<<nblk_n, 256, 0, stream>>>(cnt, dinv);
  k_padW2<<<(DIM_H * DIM_CP + 255) / 256, 256, 0, stream>>>(W2, W2p);
  k_prepW1<<<64, 256, 0, stream>>>(W1, W1f);

  // layer 1 (MFMA, bf16 LDS tile staged once, bf16 output)
  k_gemm1<<<nblk_g1, 256, 0, stream>>>(x, W1f, dinv, h1b);
  k_agg1_gather<<<nblk_nw, 256, 0, stream>>>(h1b, dinv, b1, row_start, cnt, sorted_src, agg1);

  // layer 2 (+ fused log_softmax), bf16 intermediate
  k_gemm2<<<nblk_g2, 192, 0, stream>>>(agg1, W2p, dinv, h2b);
  k_agg2_gather<<<nblk_nw, 256, 0, stream>>>(h2b, dinv, b2, row_start, cnt, sorted_src, out);
}

// Round 19
// 223.199 us; speedup vs baseline: 1.4164x; 1.0585x over previous
//
#include <hip/hip_runtime.h>
#include <math.h>

#define N_NODES 100000
#define N_EDGES 1600000
#define DIM_IN  256
#define DIM_H   64
#define DIM_C   47
#define DIM_CP  48                            // padded h2 row stride (96B bf16)
#define NB       8                            // coarse dst buckets
#define BUCKET_W 12500                        // nodes per bucket
#define BCAP     204000                       // per-bucket capacity (9.5 sigma)
#define CHUNK_P1 1024                         // edges per pass-1 block (4/thread)
#define SEG_P2   2048                         // bucket-buf segment per pass-2a block
#define NSEG_P2  100                          // segments per bucket
#define CHUNK_NODES 250                       // nodes per fine chunk
#define NCHUNK   400                          // N_NODES / 250
#define CCAP     4608                         // per-chunk edge capacity
#define XBP      264                          // bf16 x-tile row stride (+8 pad)

typedef __attribute__((ext_vector_type(8))) short bf16x8;
typedef __attribute__((ext_vector_type(4))) float f32x4;

// RNE float -> bf16 bits
static __device__ __forceinline__ unsigned short f2bf(float f) {
  unsigned u = __builtin_bit_cast(unsigned, f);
  u += 0x7FFFu + ((u >> 16) & 1u);
  return (unsigned short)(u >> 16);
}
static __device__ __forceinline__ float bf2f(unsigned short h) {
  unsigned u = ((unsigned)h) << 16;
  return __builtin_bit_cast(float, u);
}
static __device__ __forceinline__ float blo(unsigned u) {
  return __builtin_bit_cast(float, u << 16);
}
static __device__ __forceinline__ float bhi(unsigned u) {
  return __builtin_bit_cast(float, u & 0xffff0000u);
}

// ---------- zero the counters ----------
__global__ __launch_bounds__(512) void k_zero(int* __restrict__ bucket_cur,
                                              int* __restrict__ chunk_cur) {
  if (threadIdx.x < NB) bucket_cur[threadIdx.x] = 0;
  if (threadIdx.x < NCHUNK) chunk_cur[threadIdx.x] = 0;
}

// ---------- pass 1: coarse octant binning (dense reservation writes) ----------
__global__ __launch_bounds__(256) void k_bin(const int* __restrict__ src,
                                             const int* __restrict__ dst,
                                             int* __restrict__ bucket_cur,
                                             unsigned* __restrict__ bucket_buf) {
  __shared__ int lcnt[NB], lbase[NB], lcur[NB];
  if (threadIdx.x < NB) lcnt[threadIdx.x] = 0;
  __syncthreads();
  const int base = blockIdx.x * CHUNK_P1 + threadIdx.x;
  int dreg[4], sreg[4];
#pragma unroll
  for (int it = 0; it < 4; ++it) {
    int e = base + it * 256;
    int d = -1, s = 0;
    if (e < N_EDGES) { d = dst[e]; s = src[e]; }
    dreg[it] = d; sreg[it] = s;
    if (d >= 0) atomicAdd(&lcnt[d / BUCKET_W], 1);
  }
  __syncthreads();
  if (threadIdx.x < NB) {
    lbase[threadIdx.x] = atomicAdd(&bucket_cur[threadIdx.x], lcnt[threadIdx.x]);
    lcur[threadIdx.x] = 0;
  }
  __syncthreads();
#pragma unroll
  for (int it = 0; it < 4; ++it) {
    int d = dreg[it];
    if (d >= 0) {
      int b = d / BUCKET_W;
      int r = atomicAdd(&lcur[b], 1);
      unsigned pack = ((unsigned)(d - b * BUCKET_W) << 17) | (unsigned)sreg[it];
      bucket_buf[(size_t)b * BCAP + lbase[b] + r] = pack;
    }
  }
}

// ---------- pass 2a: bucket -> 50 fine chunks (dense reservation writes) ----------
__global__ __launch_bounds__(256) void k_bin2(const unsigned* __restrict__ bucket_buf,
                                              const int* __restrict__ bucket_cnt,
                                              int* __restrict__ chunk_cur,
                                              unsigned* __restrict__ chunk_buf) {
  const int b   = blockIdx.x / NSEG_P2;
  const int seg = blockIdx.x % NSEG_P2;
  const int n_b = bucket_cnt[b];
  const int s0  = seg * SEG_P2;
  const int s1  = (n_b < s0 + SEG_P2) ? n_b : (s0 + SEG_P2);
  __shared__ int lcnt[50], lbase[50], lcur[50];
  if (threadIdx.x < 50) lcnt[threadIdx.x] = 0;
  __syncthreads();
  unsigned preg[8]; int creg[8];
#pragma unroll
  for (int it = 0; it < 8; ++it) {
    int i = s0 + it * 256 + (int)threadIdx.x;
    unsigned p = 0; int cl = -1;
    if (i < s1) { p = bucket_buf[(size_t)b * BCAP + i]; cl = (int)(p >> 17) / CHUNK_NODES; atomicAdd(&lcnt[cl], 1); }
    preg[it] = p; creg[it] = cl;
  }
  __syncthreads();
  if (threadIdx.x < 50) {
    lbase[threadIdx.x] = atomicAdd(&chunk_cur[b * 50 + threadIdx.x], lcnt[threadIdx.x]);
    lcur[threadIdx.x] = 0;
  }
  __syncthreads();
#pragma unroll
  for (int it = 0; it < 8; ++it) {
    int cl = creg[it];
    if (cl >= 0) {
      unsigned p = preg[it];
      int dl = (int)(p >> 17) - cl * CHUNK_NODES;   // 0..249 within chunk
      int r = atomicAdd(&lcur[cl], 1);
      chunk_buf[(size_t)(b * 50 + cl) * CCAP + lbase[cl] + r] =
          ((unsigned)dl << 17) | (p & 0x1FFFFu);
    }
  }
}

// ---------- exclusive scan of the 400 chunk counts ----------
__global__ __launch_bounds__(512) void k_scan_chunks(const int* __restrict__ chunk_cur,
                                                     int* __restrict__ chunk_base) {
  __shared__ int ls[512];
  const int tid = threadIdx.x;
  int v = (tid < NCHUNK) ? chunk_cur[tid] : 0;
  ls[tid] = v;
  __syncthreads();
  for (int off = 1; off < 512; off <<= 1) {
    int u = (tid >= off) ? ls[tid - off] : 0;
    __syncthreads();
    ls[tid] += u;
    __syncthreads();
  }
  if (tid < NCHUNK) chunk_base[tid] = ls[tid] - v;
}

// ---------- pass 2b: per-chunk LDS counting sort; sequential global writes ----------
__global__ __launch_bounds__(256) void k_sort_chunk(const unsigned* __restrict__ chunk_buf,
                                                    const int* __restrict__ chunk_cur,
                                                    const int* __restrict__ chunk_base,
                                                    int* __restrict__ cnt,
                                                    int* __restrict__ row_start,
                                                    int* __restrict__ sorted_src) {
  const int c    = blockIdx.x;
  const int n_c  = chunk_cur[c];
  const int base = chunk_base[c];
  const unsigned* buf = chunk_buf + (size_t)c * CCAP;
  __shared__ int cntA[256], exclA[256], curA[256];
  __shared__ int sortedL[CCAP];
  const int tid = threadIdx.x;
  cntA[tid] = 0; curA[tid] = 0;
  __syncthreads();
  for (int i = tid; i < n_c; i += 256) atomicAdd(&cntA[buf[i] >> 17], 1);
  __syncthreads();
  int myc = cntA[tid];
  exclA[tid] = myc;
  __syncthreads();
  for (int off = 1; off < 256; off <<= 1) {
    int u = (tid >= off) ? exclA[tid - off] : 0;
    __syncthreads();
    exclA[tid] += u;
    __syncthreads();
  }
  int excl = exclA[tid] - myc;
  if (tid < CHUNK_NODES) {
    int n = c * CHUNK_NODES + tid;
    cnt[n] = myc;
    row_start[n] = base + excl;
  }
  __syncthreads();
  exclA[tid] = excl;
  __syncthreads();
  for (int i = tid; i < n_c; i += 256) {
    unsigned p = buf[i];
    int dl = (int)(p >> 17);
    int pos = exclA[dl] + atomicAdd(&curA[dl], 1);
    sortedL[pos] = (int)(p & 0x1FFFFu);
  }
  __syncthreads();
  for (int i = tid; i < n_c; i += 256) sorted_src[base + i] = sortedL[i];
}

// ---------- dinv = rsqrt(deg+1) ----------
__global__ __launch_bounds__(256) void k_dinv(const int* __restrict__ cnt,
                                              float* __restrict__ dinv) {
  int i = blockIdx.x * 256 + threadIdx.x;
  if (i < N_NODES) dinv[i] = rsqrtf((float)cnt[i] + 1.0f);
}

// ---------- zero the sentinel row (index N_NODES) of h1b ----------
__global__ __launch_bounds__(64) void k_zrow(unsigned short* __restrict__ h1b) {
  h1b[(size_t)N_NODES * DIM_H + threadIdx.x] = 0;
}

// ---------- pad W2 (64x47) into W2p (64x48, zero pad col) ----------
__global__ __launch_bounds__(256) void k_padW2(const float* __restrict__ W2,
                                               float* __restrict__ W2p) {
  int i = blockIdx.x * 256 + threadIdx.x;
  if (i >= DIM_H * DIM_CP) return;
  int k = i / DIM_CP, j = i % DIM_CP;
  W2p[i] = (j < DIM_C) ? W2[k * DIM_C + j] : 0.f;
}

// ---------- pre-swizzle W1 into per-lane MFMA B-fragment order ----------
__global__ __launch_bounds__(256) void k_prepW1(const float* __restrict__ W1,
                                                short* __restrict__ W1f) {
  int i = blockIdx.x * 256 + threadIdx.x;
  if (i >= 4 * 8 * 64 * 8) return;
  int e    = i & 7;
  int lane = (i >> 3) & 63;
  int ks   = (i >> 9) & 7;
  int wv   = i >> 12;
  int col  = wv * 16 + (lane & 15);
  int k    = ks * 32 + (lane >> 4) * 8 + e;
  W1f[i] = (short)f2bf(W1[k * DIM_H + col]);
}

// ---------- layer 1 GEMM on matrix cores: h1b = bf16(dinv[n] * (x @ W1)) ----------
__global__ __launch_bounds__(256) void k_gemm1(const float* __restrict__ x,
                                               const short* __restrict__ W1f,
                                               const float* __restrict__ dinv,
                                               unsigned short* __restrict__ h1b) {
  __shared__ unsigned short xb[64][XBP];      // 33792B
  const int lane = threadIdx.x & 63;
  const int wv   = threadIdx.x >> 6;
  const int m16  = lane & 15;
  const int kb   = lane >> 4;                 // 0..3
  const int base_row = blockIdx.x * 64;

#pragma unroll 4
  for (int i = 0; i < 16; ++i) {
    int r = i * 4 + wv;
    int grow = base_row + r;
    if (grow >= N_NODES) grow = N_NODES - 1;
    float4 v = *(const float4*)(x + (size_t)grow * DIM_IN + lane * 4);
    ushort4 b;
    b.x = f2bf(v.x); b.y = f2bf(v.y); b.z = f2bf(v.z); b.w = f2bf(v.w);
    *(ushort4*)&xb[r][lane * 4] = b;
  }
  __syncthreads();

  const bf16x8* wf = (const bf16x8*)W1f + (size_t)wv * 8 * 64 + lane;
  f32x4 c0 = {0.f, 0.f, 0.f, 0.f}, c1 = c0, c2 = c0, c3 = c0;
#pragma unroll
  for (int ks = 0; ks < 8; ++ks) {
    bf16x8 bb = wf[ks * 64];
#pragma unroll
    for (int rg = 0; rg < 4; ++rg) {
      bf16x8 af = *(const bf16x8*)&xb[rg * 16 + m16][ks * 32 + kb * 8];
      if (rg == 0) c0 = __builtin_amdgcn_mfma_f32_16x16x32_bf16(af, bb, c0, 0, 0, 0);
      if (rg == 1) c1 = __builtin_amdgcn_mfma_f32_16x16x32_bf16(af, bb, c1, 0, 0, 0);
      if (rg == 2) c2 = __builtin_amdgcn_mfma_f32_16x16x32_bf16(af, bb, c2, 0, 0, 0);
      if (rg == 3) c3 = __builtin_amdgcn_mfma_f32_16x16x32_bf16(af, bb, c3, 0, 0, 0);
    }
  }

  const int j0 = wv * 16 + m16;               // output column
#pragma unroll
  for (int rg = 0; rg < 4; ++rg) {
    f32x4 c = (rg == 0) ? c0 : (rg == 1) ? c1 : (rg == 2) ? c2 : c3;
#pragma unroll
    for (int r = 0; r < 4; ++r) {
      int row = base_row + rg * 16 + kb * 4 + r;
      if (row < N_NODES) h1b[(size_t)row * DIM_H + j0] = f2bf(c[r] * dinv[row]);
    }
  }
}

// ---------- agg1 gather: slot-gather (8 rows in flight per load instruction) ----------
// lane = (slot=l>>3, grp=l&7); lane reads uint4 = channels [8grp,8grp+8) of row
// k = 8r+slot (k=0 self, k<=deg edge, else zero sentinel row N_NODES). Partial
// sums are combined via a per-wave LDS transpose (no shfl, no permutation);
// output f32 agg1 in natural channel order, identical semantics to R16.
__global__ __launch_bounds__(256) void k_agg1_gather(const unsigned short* __restrict__ h1b,
                                                     const float* __restrict__ dinv,
                                                     const float* __restrict__ b1,
                                                     const int* __restrict__ row_start,
                                                     const int* __restrict__ cnt,
                                                     const int* __restrict__ sorted_src,
                                                     float* __restrict__ agg1) {
  __shared__ float red[4][8][72];             // [wave][slot][channel], padded
  const int wv   = threadIdx.x >> 6;
  const int n    = blockIdx.x * 4 + wv;       // grid exact: 25000*4 == N_NODES
  const int lane = threadIdx.x & 63;
  const int slot = lane >> 3, grp = lane & 7;
  const int start = row_start[n];
  const int deg   = cnt[n];
  const int rounds = (deg + 8) >> 3;          // ceil((deg+1)/8)

  float p0 = 0.f, p1 = 0.f, p2 = 0.f, p3 = 0.f, p4 = 0.f, p5 = 0.f, p6 = 0.f, p7 = 0.f;
  int row0 = (slot == 0) ? n : ((slot <= deg) ? sorted_src[start + slot - 1] : N_NODES);
  uint4 q = *((const uint4*)(h1b + (size_t)row0 * DIM_H) + grp);
  for (int r = 1; r < rounds; ++r) {
    int k = r * 8 + slot;
    int row = (k <= deg) ? sorted_src[start + k - 1] : N_NODES;
    uint4 qn = *((const uint4*)(h1b + (size_t)row * DIM_H) + grp);
    p0 += blo(q.x); p1 += bhi(q.x); p2 += blo(q.y); p3 += bhi(q.y);
    p4 += blo(q.z); p5 += bhi(q.z); p6 += blo(q.w); p7 += bhi(q.w);
    q = qn;
  }
  p0 += blo(q.x); p1 += bhi(q.x); p2 += blo(q.y); p3 += bhi(q.y);
  p4 += blo(q.z); p5 += bhi(q.z); p6 += blo(q.w); p7 += bhi(q.w);

  float* rs = &red[wv][slot][grp * 8];
  rs[0] = p0; rs[1] = p1; rs[2] = p2; rs[3] = p3;
  rs[4] = p4; rs[5] = p5; rs[6] = p6; rs[7] = p7;
  __syncthreads();
  float v = 0.f;
#pragma unroll
  for (int s = 0; s < 8; ++s) v += red[wv][s][lane];
  agg1[(size_t)n * DIM_H + lane] = dinv[n] * v + b1[lane];
}

// ---------- layer 2 GEMM + ReLU + dinv pre-scale -> bf16 h2b (R16-exact) ----------
__global__ __launch_bounds__(192) void k_gemm2(const float* __restrict__ agg1,
                                               const float* __restrict__ W2p,
                                               const float* __restrict__ dinv,
                                               unsigned short* __restrict__ h2b) {
  const int lane = threadIdx.x & 63;
  const int j0   = __builtin_amdgcn_readfirstlane((threadIdx.x >> 6) * 16);
  int row = blockIdx.x * 64 + lane;
  if (row >= N_NODES) row = N_NODES - 1;
  const float4* xr = (const float4*)(agg1 + (size_t)row * DIM_H);

  float4 xv[16];
#pragma unroll
  for (int k4 = 0; k4 < 16; ++k4) xv[k4] = xr[k4];
  __builtin_amdgcn_sched_barrier(0);

  float acc[16];
#pragma unroll
  for (int j = 0; j < 16; ++j) acc[j] = 0.f;

#pragma unroll
  for (int k4 = 0; k4 < DIM_H / 4; ++k4) {
    float4 v = xv[k4];
    v.x = fmaxf(v.x, 0.f); v.y = fmaxf(v.y, 0.f);
    v.z = fmaxf(v.z, 0.f); v.w = fmaxf(v.w, 0.f);
#pragma unroll
    for (int kk = 0; kk < 4; ++kk) {
      float xk = (kk == 0) ? v.x : (kk == 1) ? v.y : (kk == 2) ? v.z : v.w;
      const float* wrow = W2p + (size_t)(4 * k4 + kk) * DIM_CP + j0;  // uniform -> s_load
#pragma unroll
      for (int j = 0; j < 16; ++j)
        acc[j] = fmaf(xk, wrow[j], acc[j]);
    }
  }

  float di = dinv[row];
  unsigned* outp = (unsigned*)(h2b + (size_t)row * DIM_CP + j0);
#pragma unroll
  for (int p = 0; p < 8; ++p) {
    unsigned lo = f2bf(di * acc[2 * p]);
    unsigned hi = f2bf(di * acc[2 * p + 1]);
    outp[p] = lo | (hi << 16);
  }
}

// ---------- agg2 gather + fused log_softmax (R16-exact) ----------
__global__ __launch_bounds__(256) void k_agg2_gather(const unsigned short* __restrict__ h2b,
                                                     const float* __restrict__ dinv,
                                                     const float* __restrict__ b2,
                                                     const int* __restrict__ row_start,
                                                     const int* __restrict__ cnt,
                                                     const int* __restrict__ sorted_src,
                                                     float* __restrict__ out) {
  int n = blockIdx.x * 4 + (threadIdx.x >> 6);
  int j = threadIdx.x & 63;
  if (n >= N_NODES) return;
  int jj = (j < DIM_C) ? j : DIM_C;  // lanes >=47 read the zero pad
  int start = row_start[n];
  int deg   = cnt[n];
  float acc0 = bf2f(h2b[(size_t)n * DIM_CP + jj]);  // self term
  float acc1 = 0.f, acc2 = 0.f, acc3 = 0.f;
  float acc4 = 0.f, acc5 = 0.f, acc6 = 0.f, acc7 = 0.f;
  int k = 0;
  for (; k + 8 <= deg; k += 8) {
    int s0 = sorted_src[start + k + 0];
    int s1 = sorted_src[start + k + 1];
    int s2 = sorted_src[start + k + 2];
    int s3 = sorted_src[start + k + 3];
    int s4 = sorted_src[start + k + 4];
    int s5 = sorted_src[start + k + 5];
    int s6 = sorted_src[start + k + 6];
    int s7 = sorted_src[start + k + 7];
    acc0 += bf2f(h2b[(size_t)s0 * DIM_CP + jj]);
    acc1 += bf2f(h2b[(size_t)s1 * DIM_CP + jj]);
    acc2 += bf2f(h2b[(size_t)s2 * DIM_CP + jj]);
    acc3 += bf2f(h2b[(size_t)s3 * DIM_CP + jj]);
    acc4 += bf2f(h2b[(size_t)s4 * DIM_CP + jj]);
    acc5 += bf2f(h2b[(size_t)s5 * DIM_CP + jj]);
    acc6 += bf2f(h2b[(size_t)s6 * DIM_CP + jj]);
    acc7 += bf2f(h2b[(size_t)s7 * DIM_CP + jj]);
  }
  for (; k + 2 <= deg; k += 2) {
    int s0 = sorted_src[start + k + 0];
    int s1 = sorted_src[start + k + 1];
    acc0 += bf2f(h2b[(size_t)s0 * DIM_CP + jj]);
    acc1 += bf2f(h2b[(size_t)s1 * DIM_CP + jj]);
  }
  for (; k < deg; ++k)
    acc0 += bf2f(h2b[(size_t)sorted_src[start + k] * DIM_CP + jj]);
  float di = dinv[n];
  float acc = di * (((acc0 + acc1) + (acc2 + acc3)) + ((acc4 + acc5) + (acc6 + acc7)))
            + ((j < DIM_C) ? b2[jj] : 0.f);

  // fused log_softmax over the 47 classes
  float v = (j < DIM_C) ? acc : -INFINITY;
  float m = v;
  for (int o = 32; o; o >>= 1) m = fmaxf(m, __shfl_xor(m, o));
  float ex = (j < DIM_C) ? __expf(v - m) : 0.0f;
  float s = ex;
  for (int o = 32; o; o >>= 1) s += __shfl_xor(s, o);
  if (j < DIM_C) out[(size_t)n * DIM_C + j] = v - m - __logf(s);
}

extern "C" void kernel_launch(void* const* d_in, const int* in_sizes, int n_in,
                              void* d_out, int out_size, void* d_ws, size_t ws_size,
                              hipStream_t stream) {
  const float* x  = (const float*)d_in[0];
  const float* W1 = (const float*)d_in[1];
  const float* b1 = (const float*)d_in[2];
  const float* W2 = (const float*)d_in[3];
  const float* b2 = (const float*)d_in[4];
  const int*   ei = (const int*)d_in[5];
  const int* src = ei;
  const int* dst = ei + N_EDGES;
  float* out = (float*)d_out;

  float* ws   = (float*)d_ws;
  float* dinv = ws;                                   // N floats
  float* W2p  = dinv + N_NODES;                       // 64*48 floats
  short* W1f  = (short*)(W2p + DIM_H * DIM_CP);       // 16384 shorts
  unsigned short* h1b = (unsigned short*)(W1f + 16384);      // (N+1)*64 bf16 (sentinel row)
  float* agg1 = (float*)(h1b + (size_t)(N_NODES + 1) * DIM_H);  // N*64 f32
  unsigned short* h2b = h1b;                          // alias: h1b dead after agg1_gather
  unsigned* chunk_buf = (unsigned*)h1b;               // alias: dead before gemm1 writes h1b
  int* ibuf        = (int*)(agg1 + (size_t)N_NODES * DIM_H);
  int* cnt         = ibuf;                            // N
  int* row_start   = cnt + N_NODES;                   // N
  int* bucket_cur  = row_start + N_NODES;             // 8 (+pad)
  int* chunk_cur   = bucket_cur + 64;                 // 400
  int* chunk_base  = chunk_cur + NCHUNK;              // 400 (+pad)
  int* sorted_src  = chunk_base + NCHUNK + 64;        // E
  unsigned* bucket_buf = (unsigned*)(sorted_src + N_EDGES);  // NB*BCAP

  const int nblk_n  = (N_NODES + 255) / 256;
  const int nblk_nw = (N_NODES + 3) / 4;              // wave-per-node gathers
  const int nblk_g1 = (N_NODES + 63) / 64;            // 64-row MFMA tiles
  const int nblk_g2 = (N_NODES + 63) / 64;            // gemm2 tiles
  const int nblk_p1 = (N_EDGES + CHUNK_P1 - 1) / CHUNK_P1;   // 1563

  // CSR build: coarse bin -> fine bin -> 400-elem scan -> per-chunk LDS sort
  k_zero<<<1, 512, 0, stream>>>(bucket_cur, chunk_cur);
  k_bin<<<nblk_p1, 256, 0, stream>>>(src, dst, bucket_cur, bucket_buf);
  k_bin2<<<NB * NSEG_P2, 256, 0, stream>>>(bucket_buf, bucket_cur, chunk_cur, chunk_buf);
  k_scan_chunks<<<1, 512, 0, stream>>>(chunk_cur, chunk_base);
  k_sort_chunk<<<NCHUNK, 256, 0, stream>>>(chunk_buf, chunk_cur, chunk_base,
                                           cnt, row_start, sorted_src);
  k_dinv<<<nblk_n, 256, 0, stream>>>(cnt, dinv);
  k_padW2<<<(DIM_H * DIM_CP + 255) / 256, 256, 0, stream>>>(W2, W2p);
  k_prepW1<<<64, 256, 0, stream>>>(W1, W1f);
  k_zrow<<<1, 64, 0, stream>>>(h1b);                  // zero sentinel (chunk_buf dead by now)

  // layer 1 (MFMA, bf16 LDS tile, bf16 output) + slot-gather agg1 (f32 out)
  k_gemm1<<<nblk_g1, 256, 0, stream>>>(x, W1f, dinv, h1b);
  k_agg1_gather<<<nblk_nw, 256, 0, stream>>>(h1b, dinv, b1, row_start, cnt, sorted_src, agg1);

  // layer 2 (+ fused log_softmax), bf16 intermediate (R16-exact)
  k_gemm2<<<nblk_g2, 192, 0, stream>>>(agg1, W2p, dinv, h2b);
  k_agg2_gather<<<nblk_nw, 256, 0, stream>>>(h2b, dinv, b2, row_start, cnt, sorted_src, out);
}

// Round 20
// 208.587 us; speedup vs baseline: 1.5156x; 1.0701x over previous
//
#include <hip/hip_runtime.h>
#include <math.h>

#define N_NODES 100000
#define N_EDGES 1600000
#define DIM_IN  256
#define DIM_H   64
#define DIM_C   47
#define DIM_CP  48                            // W2p column count (padded 47->48)
#define NB       8                            // coarse dst buckets
#define BUCKET_W 12500                        // nodes per bucket
#define BCAP     204000                       // per-bucket capacity (9.5 sigma)
#define CHUNK_P1 1024                         // edges per pass-1 block (4/thread)
#define SEG_P2   2048                         // bucket-buf segment per pass-2a block
#define NSEG_P2  100                          // segments per bucket
#define CHUNK_NODES 250                       // nodes per fine chunk
#define NCHUNK   400                          // N_NODES / 250
#define CCAP     4608                         // per-chunk edge capacity
#define XBP      264                          // bf16 x-tile row stride (+8 pad)

typedef __attribute__((ext_vector_type(8))) short bf16x8;
typedef __attribute__((ext_vector_type(4))) float f32x4;

// RNE float -> bf16 bits
static __device__ __forceinline__ unsigned short f2bf(float f) {
  unsigned u = __builtin_bit_cast(unsigned, f);
  u += 0x7FFFu + ((u >> 16) & 1u);
  return (unsigned short)(u >> 16);
}
static __device__ __forceinline__ float bf2f(unsigned short h) {
  unsigned u = ((unsigned)h) << 16;
  return __builtin_bit_cast(float, u);
}
static __device__ __forceinline__ float blo(unsigned u) {
  return __builtin_bit_cast(float, u << 16);
}
static __device__ __forceinline__ float bhi(unsigned u) {
  return __builtin_bit_cast(float, u & 0xffff0000u);
}

// ---------- zero the counters ----------
__global__ __launch_bounds__(512) void k_zero(int* __restrict__ bucket_cur,
                                              int* __restrict__ chunk_cur) {
  if (threadIdx.x < NB) bucket_cur[threadIdx.x] = 0;
  if (threadIdx.x < NCHUNK) chunk_cur[threadIdx.x] = 0;
}

// ---------- pass 1: coarse octant binning (dense reservation writes) ----------
__global__ __launch_bounds__(256) void k_bin(const int* __restrict__ src,
                                             const int* __restrict__ dst,
                                             int* __restrict__ bucket_cur,
                                             unsigned* __restrict__ bucket_buf) {
  __shared__ int lcnt[NB], lbase[NB], lcur[NB];
  if (threadIdx.x < NB) lcnt[threadIdx.x] = 0;
  __syncthreads();
  const int base = blockIdx.x * CHUNK_P1 + threadIdx.x;
  int dreg[4], sreg[4];
#pragma unroll
  for (int it = 0; it < 4; ++it) {
    int e = base + it * 256;
    int d = -1, s = 0;
    if (e < N_EDGES) { d = dst[e]; s = src[e]; }
    dreg[it] = d; sreg[it] = s;
    if (d >= 0) atomicAdd(&lcnt[d / BUCKET_W], 1);
  }
  __syncthreads();
  if (threadIdx.x < NB) {
    lbase[threadIdx.x] = atomicAdd(&bucket_cur[threadIdx.x], lcnt[threadIdx.x]);
    lcur[threadIdx.x] = 0;
  }
  __syncthreads();
#pragma unroll
  for (int it = 0; it < 4; ++it) {
    int d = dreg[it];
    if (d >= 0) {
      int b = d / BUCKET_W;
      int r = atomicAdd(&lcur[b], 1);
      unsigned pack = ((unsigned)(d - b * BUCKET_W) << 17) | (unsigned)sreg[it];
      bucket_buf[(size_t)b * BCAP + lbase[b] + r] = pack;
    }
  }
}

// ---------- pass 2a: bucket -> 50 fine chunks (dense reservation writes) ----------
__global__ __launch_bounds__(256) void k_bin2(const unsigned* __restrict__ bucket_buf,
                                              const int* __restrict__ bucket_cnt,
                                              int* __restrict__ chunk_cur,
                                              unsigned* __restrict__ chunk_buf) {
  const int b   = blockIdx.x / NSEG_P2;
  const int seg = blockIdx.x % NSEG_P2;
  const int n_b = bucket_cnt[b];
  const int s0  = seg * SEG_P2;
  const int s1  = (n_b < s0 + SEG_P2) ? n_b : (s0 + SEG_P2);
  __shared__ int lcnt[50], lbase[50], lcur[50];
  if (threadIdx.x < 50) lcnt[threadIdx.x] = 0;
  __syncthreads();
  unsigned preg[8]; int creg[8];
#pragma unroll
  for (int it = 0; it < 8; ++it) {
    int i = s0 + it * 256 + (int)threadIdx.x;
    unsigned p = 0; int cl = -1;
    if (i < s1) { p = bucket_buf[(size_t)b * BCAP + i]; cl = (int)(p >> 17) / CHUNK_NODES; atomicAdd(&lcnt[cl], 1); }
    preg[it] = p; creg[it] = cl;
  }
  __syncthreads();
  if (threadIdx.x < 50) {
    lbase[threadIdx.x] = atomicAdd(&chunk_cur[b * 50 + threadIdx.x], lcnt[threadIdx.x]);
    lcur[threadIdx.x] = 0;
  }
  __syncthreads();
#pragma unroll
  for (int it = 0; it < 8; ++it) {
    int cl = creg[it];
    if (cl >= 0) {
      unsigned p = preg[it];
      int dl = (int)(p >> 17) - cl * CHUNK_NODES;   // 0..249 within chunk
      int r = atomicAdd(&lcur[cl], 1);
      chunk_buf[(size_t)(b * 50 + cl) * CCAP + lbase[cl] + r] =
          ((unsigned)dl << 17) | (p & 0x1FFFFu);
    }
  }
}

// ---------- exclusive scan of the 400 chunk counts ----------
__global__ __launch_bounds__(512) void k_scan_chunks(const int* __restrict__ chunk_cur,
                                                     int* __restrict__ chunk_base) {
  __shared__ int ls[512];
  const int tid = threadIdx.x;
  int v = (tid < NCHUNK) ? chunk_cur[tid] : 0;
  ls[tid] = v;
  __syncthreads();
  for (int off = 1; off < 512; off <<= 1) {
    int u = (tid >= off) ? ls[tid - off] : 0;
    __syncthreads();
    ls[tid] += u;
    __syncthreads();
  }
  if (tid < NCHUNK) chunk_base[tid] = ls[tid] - v;
}

// ---------- pass 2b: per-chunk LDS counting sort; sequential global writes ----------
__global__ __launch_bounds__(256) void k_sort_chunk(const unsigned* __restrict__ chunk_buf,
                                                    const int* __restrict__ chunk_cur,
                                                    const int* __restrict__ chunk_base,
                                                    int* __restrict__ cnt,
                                                    int* __restrict__ row_start,
                                                    int* __restrict__ sorted_src) {
  const int c    = blockIdx.x;
  const int n_c  = chunk_cur[c];
  const int base = chunk_base[c];
  const unsigned* buf = chunk_buf + (size_t)c * CCAP;
  __shared__ int cntA[256], exclA[256], curA[256];
  __shared__ int sortedL[CCAP];
  const int tid = threadIdx.x;
  cntA[tid] = 0; curA[tid] = 0;
  __syncthreads();
  for (int i = tid; i < n_c; i += 256) atomicAdd(&cntA[buf[i] >> 17], 1);
  __syncthreads();
  int myc = cntA[tid];
  exclA[tid] = myc;
  __syncthreads();
  for (int off = 1; off < 256; off <<= 1) {
    int u = (tid >= off) ? exclA[tid - off] : 0;
    __syncthreads();
    exclA[tid] += u;
    __syncthreads();
  }
  int excl = exclA[tid] - myc;
  if (tid < CHUNK_NODES) {
    int n = c * CHUNK_NODES + tid;
    cnt[n] = myc;
    row_start[n] = base + excl;
  }
  __syncthreads();
  exclA[tid] = excl;
  __syncthreads();
  for (int i = tid; i < n_c; i += 256) {
    unsigned p = buf[i];
    int dl = (int)(p >> 17);
    int pos = exclA[dl] + atomicAdd(&curA[dl], 1);
    sortedL[pos] = (int)(p & 0x1FFFFu);
  }
  __syncthreads();
  for (int i = tid; i < n_c; i += 256) sorted_src[base + i] = sortedL[i];
}

// ---------- dinv = rsqrt(deg+1) ----------
__global__ __launch_bounds__(256) void k_dinv(const int* __restrict__ cnt,
                                              float* __restrict__ dinv) {
  int i = blockIdx.x * 256 + threadIdx.x;
  if (i < N_NODES) dinv[i] = rsqrtf((float)cnt[i] + 1.0f);
}

// ---------- zero the sentinel row (index N_NODES) of h1b ----------
__global__ __launch_bounds__(64) void k_zrow(unsigned short* __restrict__ h1b) {
  h1b[(size_t)N_NODES * DIM_H + threadIdx.x] = 0;
}

// ---------- pad W2 (64x47) into W2p (64x48, zero pad col) ----------
__global__ __launch_bounds__(256) void k_padW2(const float* __restrict__ W2,
                                               float* __restrict__ W2p) {
  int i = blockIdx.x * 256 + threadIdx.x;
  if (i >= DIM_H * DIM_CP) return;
  int k = i / DIM_CP, j = i % DIM_CP;
  W2p[i] = (j < DIM_C) ? W2[k * DIM_C + j] : 0.f;
}

// ---------- pre-swizzle W1 into per-lane MFMA B-fragment order ----------
__global__ __launch_bounds__(256) void k_prepW1(const float* __restrict__ W1,
                                                short* __restrict__ W1f) {
  int i = blockIdx.x * 256 + threadIdx.x;
  if (i >= 4 * 8 * 64 * 8) return;
  int e    = i & 7;
  int lane = (i >> 3) & 63;
  int ks   = (i >> 9) & 7;
  int wv   = i >> 12;
  int col  = wv * 16 + (lane & 15);
  int k    = ks * 32 + (lane >> 4) * 8 + e;
  W1f[i] = (short)f2bf(W1[k * DIM_H + col]);
}

// ---------- layer 1 GEMM on matrix cores: h1b = bf16(dinv[n] * (x @ W1)) ----------
__global__ __launch_bounds__(256) void k_gemm1(const float* __restrict__ x,
                                               const short* __restrict__ W1f,
                                               const float* __restrict__ dinv,
                                               unsigned short* __restrict__ h1b) {
  __shared__ unsigned short xb[64][XBP];      // 33792B
  const int lane = threadIdx.x & 63;
  const int wv   = threadIdx.x >> 6;
  const int m16  = lane & 15;
  const int kb   = lane >> 4;                 // 0..3
  const int base_row = blockIdx.x * 64;

#pragma unroll 4
  for (int i = 0; i < 16; ++i) {
    int r = i * 4 + wv;
    int grow = base_row + r;
    if (grow >= N_NODES) grow = N_NODES - 1;
    float4 v = *(const float4*)(x + (size_t)grow * DIM_IN + lane * 4);
    ushort4 b;
    b.x = f2bf(v.x); b.y = f2bf(v.y); b.z = f2bf(v.z); b.w = f2bf(v.w);
    *(ushort4*)&xb[r][lane * 4] = b;
  }
  __syncthreads();

  const bf16x8* wf = (const bf16x8*)W1f + (size_t)wv * 8 * 64 + lane;
  f32x4 c0 = {0.f, 0.f, 0.f, 0.f}, c1 = c0, c2 = c0, c3 = c0;
#pragma unroll
  for (int ks = 0; ks < 8; ++ks) {
    bf16x8 bb = wf[ks * 64];
#pragma unroll
    for (int rg = 0; rg < 4; ++rg) {
      bf16x8 af = *(const bf16x8*)&xb[rg * 16 + m16][ks * 32 + kb * 8];
      if (rg == 0) c0 = __builtin_amdgcn_mfma_f32_16x16x32_bf16(af, bb, c0, 0, 0, 0);
      if (rg == 1) c1 = __builtin_amdgcn_mfma_f32_16x16x32_bf16(af, bb, c1, 0, 0, 0);
      if (rg == 2) c2 = __builtin_amdgcn_mfma_f32_16x16x32_bf16(af, bb, c2, 0, 0, 0);
      if (rg == 3) c3 = __builtin_amdgcn_mfma_f32_16x16x32_bf16(af, bb, c3, 0, 0, 0);
    }
  }

  const int j0 = wv * 16 + m16;               // output column
#pragma unroll
  for (int rg = 0; rg < 4; ++rg) {
    f32x4 c = (rg == 0) ? c0 : (rg == 1) ? c1 : (rg == 2) ? c2 : c3;
#pragma unroll
    for (int r = 0; r < 4; ++r) {
      int row = base_row + rg * 16 + kb * 4 + r;
      if (row < N_NODES) h1b[(size_t)row * DIM_H + j0] = f2bf(c[r] * dinv[row]);
    }
  }
}

// ---------- agg1 gather: slot-gather (8 rows in flight per load instruction) ----------
__global__ __launch_bounds__(256) void k_agg1_gather(const unsigned short* __restrict__ h1b,
                                                     const float* __restrict__ dinv,
                                                     const float* __restrict__ b1,
                                                     const int* __restrict__ row_start,
                                                     const int* __restrict__ cnt,
                                                     const int* __restrict__ sorted_src,
                                                     float* __restrict__ agg1) {
  __shared__ float red[4][8][72];             // [wave][slot][channel], padded
  const int wv   = threadIdx.x >> 6;
  const int n    = blockIdx.x * 4 + wv;       // grid exact: 25000*4 == N_NODES
  const int lane = threadIdx.x & 63;
  const int slot = lane >> 3, grp = lane & 7;
  const int start = row_start[n];
  const int deg   = cnt[n];
  const int rounds = (deg + 8) >> 3;          // ceil((deg+1)/8)

  float p0 = 0.f, p1 = 0.f, p2 = 0.f, p3 = 0.f, p4 = 0.f, p5 = 0.f, p6 = 0.f, p7 = 0.f;
  int row0 = (slot == 0) ? n : ((slot <= deg) ? sorted_src[start + slot - 1] : N_NODES);
  uint4 q = *((const uint4*)(h1b + (size_t)row0 * DIM_H) + grp);
  for (int r = 1; r < rounds; ++r) {
    int k = r * 8 + slot;
    int row = (k <= deg) ? sorted_src[start + k - 1] : N_NODES;
    uint4 qn = *((const uint4*)(h1b + (size_t)row * DIM_H) + grp);
    p0 += blo(q.x); p1 += bhi(q.x); p2 += blo(q.y); p3 += bhi(q.y);
    p4 += blo(q.z); p5 += bhi(q.z); p6 += blo(q.w); p7 += bhi(q.w);
    q = qn;
  }
  p0 += blo(q.x); p1 += bhi(q.x); p2 += blo(q.y); p3 += bhi(q.y);
  p4 += blo(q.z); p5 += bhi(q.z); p6 += blo(q.w); p7 += bhi(q.w);

  float* rs = &red[wv][slot][grp * 8];
  rs[0] = p0; rs[1] = p1; rs[2] = p2; rs[3] = p3;
  rs[4] = p4; rs[5] = p5; rs[6] = p6; rs[7] = p7;
  __syncthreads();
  float v = 0.f;
#pragma unroll
  for (int s = 0; s < 8; ++s) v += red[wv][s][lane];
  agg1[(size_t)n * DIM_H + lane] = dinv[n] * v + b1[lane];
}

// ---------- layer 2 GEMM + ReLU + dinv pre-scale -> bf16 h2b (64-ch row stride) ----------
// Writes channels 0..47 of each 64-wide row; cols 48..63 stay stale (finite bf16,
// masked downstream). Row stride change is the only delta vs R18.
__global__ __launch_bounds__(192) void k_gemm2(const float* __restrict__ agg1,
                                               const float* __restrict__ W2p,
                                               const float* __restrict__ dinv,
                                               unsigned short* __restrict__ h2b) {
  const int lane = threadIdx.x & 63;
  const int j0   = __builtin_amdgcn_readfirstlane((threadIdx.x >> 6) * 16);
  int row = blockIdx.x * 64 + lane;
  if (row >= N_NODES) row = N_NODES - 1;
  const float4* xr = (const float4*)(agg1 + (size_t)row * DIM_H);

  float4 xv[16];
#pragma unroll
  for (int k4 = 0; k4 < 16; ++k4) xv[k4] = xr[k4];
  __builtin_amdgcn_sched_barrier(0);

  float acc[16];
#pragma unroll
  for (int j = 0; j < 16; ++j) acc[j] = 0.f;

#pragma unroll
  for (int k4 = 0; k4 < DIM_H / 4; ++k4) {
    float4 v = xv[k4];
    v.x = fmaxf(v.x, 0.f); v.y = fmaxf(v.y, 0.f);
    v.z = fmaxf(v.z, 0.f); v.w = fmaxf(v.w, 0.f);
#pragma unroll
    for (int kk = 0; kk < 4; ++kk) {
      float xk = (kk == 0) ? v.x : (kk == 1) ? v.y : (kk == 2) ? v.z : v.w;
      const float* wrow = W2p + (size_t)(4 * k4 + kk) * DIM_CP + j0;  // uniform -> s_load
#pragma unroll
      for (int j = 0; j < 16; ++j)
        acc[j] = fmaf(xk, wrow[j], acc[j]);
    }
  }

  float di = dinv[row];
  unsigned* outp = (unsigned*)(h2b + (size_t)row * DIM_H + j0);
#pragma unroll
  for (int p = 0; p < 8; ++p) {
    unsigned lo = f2bf(di * acc[2 * p]);
    unsigned hi = f2bf(di * acc[2 * p + 1]);
    outp[p] = lo | (hi << 16);
  }
}

// ---------- agg2 slot-gather + bias + fused log_softmax ----------
// Same verified slot-gather as agg1; channel c = lane after LDS transpose;
// lanes with c >= 47 masked (stale pad cols never reach the softmax).
__global__ __launch_bounds__(256) void k_agg2_gather(const unsigned short* __restrict__ h2b,
                                                     const float* __restrict__ dinv,
                                                     const float* __restrict__ b2,
                                                     const int* __restrict__ row_start,
                                                     const int* __restrict__ cnt,
                                                     const int* __restrict__ sorted_src,
                                                     float* __restrict__ out) {
  __shared__ float red[4][8][72];             // [wave][slot][channel], padded
  const int wv   = threadIdx.x >> 6;
  const int n    = blockIdx.x * 4 + wv;       // grid exact
  const int lane = threadIdx.x & 63;
  const int slot = lane >> 3, grp = lane & 7;
  const int start = row_start[n];
  const int deg   = cnt[n];
  const int rounds = (deg + 8) >> 3;

  float p0 = 0.f, p1 = 0.f, p2 = 0.f, p3 = 0.f, p4 = 0.f, p5 = 0.f, p6 = 0.f, p7 = 0.f;
  int row0 = (slot == 0) ? n : ((slot <= deg) ? sorted_src[start + slot - 1] : N_NODES);
  uint4 q = *((const uint4*)(h2b + (size_t)row0 * DIM_H) + grp);
  for (int r = 1; r < rounds; ++r) {
    int k = r * 8 + slot;
    int row = (k <= deg) ? sorted_src[start + k - 1] : N_NODES;
    uint4 qn = *((const uint4*)(h2b + (size_t)row * DIM_H) + grp);
    p0 += blo(q.x); p1 += bhi(q.x); p2 += blo(q.y); p3 += bhi(q.y);
    p4 += blo(q.z); p5 += bhi(q.z); p6 += blo(q.w); p7 += bhi(q.w);
    q = qn;
  }
  p0 += blo(q.x); p1 += bhi(q.x); p2 += blo(q.y); p3 += bhi(q.y);
  p4 += blo(q.z); p5 += bhi(q.z); p6 += blo(q.w); p7 += bhi(q.w);

  float* rs = &red[wv][slot][grp * 8];
  rs[0] = p0; rs[1] = p1; rs[2] = p2; rs[3] = p3;
  rs[4] = p4; rs[5] = p5; rs[6] = p6; rs[7] = p7;
  __syncthreads();
  float v = 0.f;
#pragma unroll
  for (int s = 0; s < 8; ++s) v += red[wv][s][lane];

  float val = (lane < DIM_C) ? (dinv[n] * v + b2[lane]) : -INFINITY;

  // fused log_softmax over the 47 classes
  float m = val;
  for (int o = 32; o; o >>= 1) m = fmaxf(m, __shfl_xor(m, o));
  float ex = (lane < DIM_C) ? __expf(val - m) : 0.0f;
  float s = ex;
  for (int o = 32; o; o >>= 1) s += __shfl_xor(s, o);
  if (lane < DIM_C) out[(size_t)n * DIM_C + lane] = val - m - __logf(s);
}

extern "C" void kernel_launch(void* const* d_in, const int* in_sizes, int n_in,
                              void* d_out, int out_size, void* d_ws, size_t ws_size,
                              hipStream_t stream) {
  const float* x  = (const float*)d_in[0];
  const float* W1 = (const float*)d_in[1];
  const float* b1 = (const float*)d_in[2];
  const float* W2 = (const float*)d_in[3];
  const float* b2 = (const float*)d_in[4];
  const int*   ei = (const int*)d_in[5];
  const int* src = ei;
  const int* dst = ei + N_EDGES;
  float* out = (float*)d_out;

  float* ws   = (float*)d_ws;
  float* dinv = ws;                                   // N floats
  float* W2p  = dinv + N_NODES;                       // 64*48 floats
  short* W1f  = (short*)(W2p + DIM_H * DIM_CP);       // 16384 shorts
  unsigned short* h1b = (unsigned short*)(W1f + 16384);      // (N+1)*64 bf16 (sentinel row)
  float* agg1 = (float*)(h1b + (size_t)(N_NODES + 1) * DIM_H);  // N*64 f32
  unsigned short* h2b = h1b;                          // alias: h1b dead after agg1_gather
  unsigned* chunk_buf = (unsigned*)h1b;               // alias: dead before gemm1 writes h1b
  int* ibuf        = (int*)(agg1 + (size_t)N_NODES * DIM_H);
  int* cnt         = ibuf;                            // N
  int* row_start   = cnt + N_NODES;                   // N
  int* bucket_cur  = row_start + N_NODES;             // 8 (+pad)
  int* chunk_cur   = bucket_cur + 64;                 // 400
  int* chunk_base  = chunk_cur + NCHUNK;              // 400 (+pad)
  int* sorted_src  = chunk_base + NCHUNK + 64;        // E
  unsigned* bucket_buf = (unsigned*)(sorted_src + N_EDGES);  // NB*BCAP

  const int nblk_n  = (N_NODES + 255) / 256;
  const int nblk_nw = (N_NODES + 3) / 4;              // wave-per-node gathers
  const int nblk_g1 = (N_NODES + 63) / 64;            // 64-row MFMA tiles
  const int nblk_g2 = (N_NODES + 63) / 64;            // gemm2 tiles
  const int nblk_p1 = (N_EDGES + CHUNK_P1 - 1) / CHUNK_P1;   // 1563

  // CSR build: coarse bin -> fine bin -> 400-elem scan -> per-chunk LDS sort
  k_zero<<<1, 512, 0, stream>>>(bucket_cur, chunk_cur);
  k_bin<<<nblk_p1, 256, 0, stream>>>(src, dst, bucket_cur, bucket_buf);
  k_bin2<<<NB * NSEG_P2, 256, 0, stream>>>(bucket_buf, bucket_cur, chunk_cur, chunk_buf);
  k_scan_chunks<<<1, 512, 0, stream>>>(chunk_cur, chunk_base);
  k_sort_chunk<<<NCHUNK, 256, 0, stream>>>(chunk_buf, chunk_cur, chunk_base,
                                           cnt, row_start, sorted_src);
  k_dinv<<<nblk_n, 256, 0, stream>>>(cnt, dinv);
  k_padW2<<<(DIM_H * DIM_CP + 255) / 256, 256, 0, stream>>>(W2, W2p);
  k_prepW1<<<64, 256, 0, stream>>>(W1, W1f);
  k_zrow<<<1, 64, 0, stream>>>(h1b);                  // zero sentinel (chunk_buf dead by now)

  // layer 1 (MFMA, bf16 LDS tile, bf16 output) + slot-gather agg1 (f32 out)
  k_gemm1<<<nblk_g1, 256, 0, stream>>>(x, W1f, dinv, h1b);
  k_agg1_gather<<<nblk_nw, 256, 0, stream>>>(h1b, dinv, b1, row_start, cnt, sorted_src, agg1);

  // layer 2 (64-ch bf16 rows) + slot-gather agg2 + fused log_softmax
  k_gemm2<<<nblk_g2, 192, 0, stream>>>(agg1, W2p, dinv, h2b);
  k_agg2_gather<<<nblk_nw, 256, 0, stream>>>(h2b, dinv, b2, row_start, cnt, sorted_src, out);
}

// Round 21
// 206.630 us; speedup vs baseline: 1.5300x; 1.0095x over previous
//
#include <hip/hip_runtime.h>
#include <math.h>

#define N_NODES 100000
#define N_EDGES 1600000
#define DIM_IN  256
#define DIM_H   64
#define DIM_C   47
#define DIM_CP  48                            // W2p column count (padded 47->48)
#define NB       8                            // coarse dst buckets
#define BUCKET_W 12500                        // nodes per bucket
#define BCAP     204000                       // per-bucket capacity (9.5 sigma)
#define CHUNK_P1 1024                         // edges per pass-1 block (4/thread)
#define SEG_P2   2048                         // bucket-buf segment per pass-2a block
#define NSEG_P2  100                          // segments per bucket
#define CHUNK_NODES 250                       // nodes per fine chunk
#define NCHUNK   400                          // N_NODES / 250
#define CCAP     4608                         // per-chunk edge capacity
#define XBP      264                          // bf16 x-tile row stride (+8 pad)

typedef __attribute__((ext_vector_type(8))) short bf16x8;
typedef __attribute__((ext_vector_type(4))) float f32x4;

// RNE float -> bf16 bits
static __device__ __forceinline__ unsigned short f2bf(float f) {
  unsigned u = __builtin_bit_cast(unsigned, f);
  u += 0x7FFFu + ((u >> 16) & 1u);
  return (unsigned short)(u >> 16);
}
static __device__ __forceinline__ float bf2f(unsigned short h) {
  unsigned u = ((unsigned)h) << 16;
  return __builtin_bit_cast(float, u);
}
static __device__ __forceinline__ float blo(unsigned u) {
  return __builtin_bit_cast(float, u << 16);
}
static __device__ __forceinline__ float bhi(unsigned u) {
  return __builtin_bit_cast(float, u & 0xffff0000u);
}

// ---------- zero the counters ----------
__global__ __launch_bounds__(512) void k_zero(int* __restrict__ bucket_cur,
                                              int* __restrict__ chunk_cur) {
  if (threadIdx.x < NB) bucket_cur[threadIdx.x] = 0;
  if (threadIdx.x < NCHUNK) chunk_cur[threadIdx.x] = 0;
}

// ---------- pass 1: coarse octant binning (dense reservation writes) ----------
__global__ __launch_bounds__(256) void k_bin(const int* __restrict__ src,
                                             const int* __restrict__ dst,
                                             int* __restrict__ bucket_cur,
                                             unsigned* __restrict__ bucket_buf) {
  __shared__ int lcnt[NB], lbase[NB], lcur[NB];
  if (threadIdx.x < NB) lcnt[threadIdx.x] = 0;
  __syncthreads();
  const int base = blockIdx.x * CHUNK_P1 + threadIdx.x;
  int dreg[4], sreg[4];
#pragma unroll
  for (int it = 0; it < 4; ++it) {
    int e = base + it * 256;
    int d = -1, s = 0;
    if (e < N_EDGES) { d = dst[e]; s = src[e]; }
    dreg[it] = d; sreg[it] = s;
    if (d >= 0) atomicAdd(&lcnt[d / BUCKET_W], 1);
  }
  __syncthreads();
  if (threadIdx.x < NB) {
    lbase[threadIdx.x] = atomicAdd(&bucket_cur[threadIdx.x], lcnt[threadIdx.x]);
    lcur[threadIdx.x] = 0;
  }
  __syncthreads();
#pragma unroll
  for (int it = 0; it < 4; ++it) {
    int d = dreg[it];
    if (d >= 0) {
      int b = d / BUCKET_W;
      int r = atomicAdd(&lcur[b], 1);
      unsigned pack = ((unsigned)(d - b * BUCKET_W) << 17) | (unsigned)sreg[it];
      bucket_buf[(size_t)b * BCAP + lbase[b] + r] = pack;
    }
  }
}

// ---------- pass 2a: bucket -> 50 fine chunks (dense reservation writes) ----------
__global__ __launch_bounds__(256) void k_bin2(const unsigned* __restrict__ bucket_buf,
                                              const int* __restrict__ bucket_cnt,
                                              int* __restrict__ chunk_cur,
                                              unsigned* __restrict__ chunk_buf) {
  const int b   = blockIdx.x / NSEG_P2;
  const int seg = blockIdx.x % NSEG_P2;
  const int n_b = bucket_cnt[b];
  const int s0  = seg * SEG_P2;
  const int s1  = (n_b < s0 + SEG_P2) ? n_b : (s0 + SEG_P2);
  __shared__ int lcnt[50], lbase[50], lcur[50];
  if (threadIdx.x < 50) lcnt[threadIdx.x] = 0;
  __syncthreads();
  unsigned preg[8]; int creg[8];
#pragma unroll
  for (int it = 0; it < 8; ++it) {
    int i = s0 + it * 256 + (int)threadIdx.x;
    unsigned p = 0; int cl = -1;
    if (i < s1) { p = bucket_buf[(size_t)b * BCAP + i]; cl = (int)(p >> 17) / CHUNK_NODES; atomicAdd(&lcnt[cl], 1); }
    preg[it] = p; creg[it] = cl;
  }
  __syncthreads();
  if (threadIdx.x < 50) {
    lbase[threadIdx.x] = atomicAdd(&chunk_cur[b * 50 + threadIdx.x], lcnt[threadIdx.x]);
    lcur[threadIdx.x] = 0;
  }
  __syncthreads();
#pragma unroll
  for (int it = 0; it < 8; ++it) {
    int cl = creg[it];
    if (cl >= 0) {
      unsigned p = preg[it];
      int dl = (int)(p >> 17) - cl * CHUNK_NODES;   // 0..249 within chunk
      int r = atomicAdd(&lcur[cl], 1);
      chunk_buf[(size_t)(b * 50 + cl) * CCAP + lbase[cl] + r] =
          ((unsigned)dl << 17) | (p & 0x1FFFFu);
    }
  }
}

// ---------- exclusive scan of the 400 chunk counts ----------
__global__ __launch_bounds__(512) void k_scan_chunks(const int* __restrict__ chunk_cur,
                                                     int* __restrict__ chunk_base) {
  __shared__ int ls[512];
  const int tid = threadIdx.x;
  int v = (tid < NCHUNK) ? chunk_cur[tid] : 0;
  ls[tid] = v;
  __syncthreads();
  for (int off = 1; off < 512; off <<= 1) {
    int u = (tid >= off) ? ls[tid - off] : 0;
    __syncthreads();
    ls[tid] += u;
    __syncthreads();
  }
  if (tid < NCHUNK) chunk_base[tid] = ls[tid] - v;
}

// ---------- pass 2b: per-chunk LDS counting sort; sequential global writes ----------
__global__ __launch_bounds__(256) void k_sort_chunk(const unsigned* __restrict__ chunk_buf,
                                                    const int* __restrict__ chunk_cur,
                                                    const int* __restrict__ chunk_base,
                                                    int* __restrict__ cnt,
                                                    int* __restrict__ row_start,
                                                    int* __restrict__ sorted_src) {
  const int c    = blockIdx.x;
  const int n_c  = chunk_cur[c];
  const int base = chunk_base[c];
  const unsigned* buf = chunk_buf + (size_t)c * CCAP;
  __shared__ int cntA[256], exclA[256], curA[256];
  __shared__ int sortedL[CCAP];
  const int tid = threadIdx.x;
  cntA[tid] = 0; curA[tid] = 0;
  __syncthreads();
  for (int i = tid; i < n_c; i += 256) atomicAdd(&cntA[buf[i] >> 17], 1);
  __syncthreads();
  int myc = cntA[tid];
  exclA[tid] = myc;
  __syncthreads();
  for (int off = 1; off < 256; off <<= 1) {
    int u = (tid >= off) ? exclA[tid - off] : 0;
    __syncthreads();
    exclA[tid] += u;
    __syncthreads();
  }
  int excl = exclA[tid] - myc;
  if (tid < CHUNK_NODES) {
    int n = c * CHUNK_NODES + tid;
    cnt[n] = myc;
    row_start[n] = base + excl;
  }
  __syncthreads();
  exclA[tid] = excl;
  __syncthreads();
  for (int i = tid; i < n_c; i += 256) {
    unsigned p = buf[i];
    int dl = (int)(p >> 17);
    int pos = exclA[dl] + atomicAdd(&curA[dl], 1);
    sortedL[pos] = (int)(p & 0x1FFFFu);
  }
  __syncthreads();
  for (int i = tid; i < n_c; i += 256) sorted_src[base + i] = sortedL[i];
}

// ---------- dinv = rsqrt(deg+1) ----------
__global__ __launch_bounds__(256) void k_dinv(const int* __restrict__ cnt,
                                              float* __restrict__ dinv) {
  int i = blockIdx.x * 256 + threadIdx.x;
  if (i < N_NODES) dinv[i] = rsqrtf((float)cnt[i] + 1.0f);
}

// ---------- zero the sentinel row (index N_NODES) of h1b ----------
__global__ __launch_bounds__(64) void k_zrow(unsigned short* __restrict__ h1b) {
  h1b[(size_t)N_NODES * DIM_H + threadIdx.x] = 0;
}

// ---------- pad W2 (64x47) into W2p (64x48, zero pad col) ----------
__global__ __launch_bounds__(256) void k_padW2(const float* __restrict__ W2,
                                               float* __restrict__ W2p) {
  int i = blockIdx.x * 256 + threadIdx.x;
  if (i >= DIM_H * DIM_CP) return;
  int k = i / DIM_CP, j = i % DIM_CP;
  W2p[i] = (j < DIM_C) ? W2[k * DIM_C + j] : 0.f;
}

// ---------- pre-swizzle W1 into per-lane MFMA B-fragment order ----------
__global__ __launch_bounds__(256) void k_prepW1(const float* __restrict__ W1,
                                                short* __restrict__ W1f) {
  int i = blockIdx.x * 256 + threadIdx.x;
  if (i >= 4 * 8 * 64 * 8) return;
  int e    = i & 7;
  int lane = (i >> 3) & 63;
  int ks   = (i >> 9) & 7;
  int wv   = i >> 12;
  int col  = wv * 16 + (lane & 15);
  int k    = ks * 32 + (lane >> 4) * 8 + e;
  W1f[i] = (short)f2bf(W1[k * DIM_H + col]);
}

// ---------- layer 1 GEMM on matrix cores: h1b = bf16(dinv[n] * (x @ W1)) ----------
__global__ __launch_bounds__(256) void k_gemm1(const float* __restrict__ x,
                                               const short* __restrict__ W1f,
                                               const float* __restrict__ dinv,
                                               unsigned short* __restrict__ h1b) {
  __shared__ unsigned short xb[64][XBP];      // 33792B
  const int lane = threadIdx.x & 63;
  const int wv   = threadIdx.x >> 6;
  const int m16  = lane & 15;
  const int kb   = lane >> 4;                 // 0..3
  const int base_row = blockIdx.x * 64;

#pragma unroll 4
  for (int i = 0; i < 16; ++i) {
    int r = i * 4 + wv;
    int grow = base_row + r;
    if (grow >= N_NODES) grow = N_NODES - 1;
    float4 v = *(const float4*)(x + (size_t)grow * DIM_IN + lane * 4);
    ushort4 b;
    b.x = f2bf(v.x); b.y = f2bf(v.y); b.z = f2bf(v.z); b.w = f2bf(v.w);
    *(ushort4*)&xb[r][lane * 4] = b;
  }
  __syncthreads();

  const bf16x8* wf = (const bf16x8*)W1f + (size_t)wv * 8 * 64 + lane;
  f32x4 c0 = {0.f, 0.f, 0.f, 0.f}, c1 = c0, c2 = c0, c3 = c0;
#pragma unroll
  for (int ks = 0; ks < 8; ++ks) {
    bf16x8 bb = wf[ks * 64];
#pragma unroll
    for (int rg = 0; rg < 4; ++rg) {
      bf16x8 af = *(const bf16x8*)&xb[rg * 16 + m16][ks * 32 + kb * 8];
      if (rg == 0) c0 = __builtin_amdgcn_mfma_f32_16x16x32_bf16(af, bb, c0, 0, 0, 0);
      if (rg == 1) c1 = __builtin_amdgcn_mfma_f32_16x16x32_bf16(af, bb, c1, 0, 0, 0);
      if (rg == 2) c2 = __builtin_amdgcn_mfma_f32_16x16x32_bf16(af, bb, c2, 0, 0, 0);
      if (rg == 3) c3 = __builtin_amdgcn_mfma_f32_16x16x32_bf16(af, bb, c3, 0, 0, 0);
    }
  }

  const int j0 = wv * 16 + m16;               // output column
#pragma unroll
  for (int rg = 0; rg < 4; ++rg) {
    f32x4 c = (rg == 0) ? c0 : (rg == 1) ? c1 : (rg == 2) ? c2 : c3;
#pragma unroll
    for (int r = 0; r < 4; ++r) {
      int row = base_row + rg * 16 + kb * 4 + r;
      if (row < N_NODES) h1b[(size_t)row * DIM_H + j0] = f2bf(c[r] * dinv[row]);
    }
  }
}

// ---------- agg1 gather: slot-gather with index prefetch pipeline ----------
// Round r's row load no longer waits on round r's index load: the index for
// round r+1 is issued BEFORE the row load of round r (dynamic trip count blocks
// compiler cross-iteration pipelining, so done manually).
__global__ __launch_bounds__(256) void k_agg1_gather(const unsigned short* __restrict__ h1b,
                                                     const float* __restrict__ dinv,
                                                     const float* __restrict__ b1,
                                                     const int* __restrict__ row_start,
                                                     const int* __restrict__ cnt,
                                                     const int* __restrict__ sorted_src,
                                                     float* __restrict__ agg1) {
  __shared__ float red[4][8][72];             // [wave][slot][channel], padded
  const int wv   = threadIdx.x >> 6;
  const int n    = blockIdx.x * 4 + wv;       // grid exact: 25000*4 == N_NODES
  const int lane = threadIdx.x & 63;
  const int slot = lane >> 3, grp = lane & 7;
  const int start = row_start[n];
  const int deg   = cnt[n];
  const int rounds = (deg + 8) >> 3;          // ceil((deg+1)/8)

  float p0 = 0.f, p1 = 0.f, p2 = 0.f, p3 = 0.f, p4 = 0.f, p5 = 0.f, p6 = 0.f, p7 = 0.f;
  int row0 = (slot == 0) ? n : ((slot <= deg) ? sorted_src[start + slot - 1] : N_NODES);
  int idxn = (8 + slot <= deg) ? sorted_src[start + 8 + slot - 1] : N_NODES;  // round-1 idx
  uint4 q = *((const uint4*)(h1b + (size_t)row0 * DIM_H) + grp);
  for (int r = 1; r < rounds; ++r) {
    int row = idxn;
    int kn = (r + 1) * 8 + slot;              // prefetch round r+1's index
    idxn = (kn <= deg) ? sorted_src[start + kn - 1] : N_NODES;
    uint4 qn = *((const uint4*)(h1b + (size_t)row * DIM_H) + grp);
    p0 += blo(q.x); p1 += bhi(q.x); p2 += blo(q.y); p3 += bhi(q.y);
    p4 += blo(q.z); p5 += bhi(q.z); p6 += blo(q.w); p7 += bhi(q.w);
    q = qn;
  }
  p0 += blo(q.x); p1 += bhi(q.x); p2 += blo(q.y); p3 += bhi(q.y);
  p4 += blo(q.z); p5 += bhi(q.z); p6 += blo(q.w); p7 += bhi(q.w);

  float* rs = &red[wv][slot][grp * 8];
  rs[0] = p0; rs[1] = p1; rs[2] = p2; rs[3] = p3;
  rs[4] = p4; rs[5] = p5; rs[6] = p6; rs[7] = p7;
  __syncthreads();
  float v = 0.f;
#pragma unroll
  for (int s = 0; s < 8; ++s) v += red[wv][s][lane];
  agg1[(size_t)n * DIM_H + lane] = dinv[n] * v + b1[lane];
}

// ---------- layer 2 GEMM + ReLU + dinv pre-scale -> bf16 h2b (64-ch row stride) ----------
__global__ __launch_bounds__(192) void k_gemm2(const float* __restrict__ agg1,
                                               const float* __restrict__ W2p,
                                               const float* __restrict__ dinv,
                                               unsigned short* __restrict__ h2b) {
  const int lane = threadIdx.x & 63;
  const int j0   = __builtin_amdgcn_readfirstlane((threadIdx.x >> 6) * 16);
  int row = blockIdx.x * 64 + lane;
  if (row >= N_NODES) row = N_NODES - 1;
  const float4* xr = (const float4*)(agg1 + (size_t)row * DIM_H);

  float4 xv[16];
#pragma unroll
  for (int k4 = 0; k4 < 16; ++k4) xv[k4] = xr[k4];
  __builtin_amdgcn_sched_barrier(0);

  float acc[16];
#pragma unroll
  for (int j = 0; j < 16; ++j) acc[j] = 0.f;

#pragma unroll
  for (int k4 = 0; k4 < DIM_H / 4; ++k4) {
    float4 v = xv[k4];
    v.x = fmaxf(v.x, 0.f); v.y = fmaxf(v.y, 0.f);
    v.z = fmaxf(v.z, 0.f); v.w = fmaxf(v.w, 0.f);
#pragma unroll
    for (int kk = 0; kk < 4; ++kk) {
      float xk = (kk == 0) ? v.x : (kk == 1) ? v.y : (kk == 2) ? v.z : v.w;
      const float* wrow = W2p + (size_t)(4 * k4 + kk) * DIM_CP + j0;  // uniform -> s_load
#pragma unroll
      for (int j = 0; j < 16; ++j)
        acc[j] = fmaf(xk, wrow[j], acc[j]);
    }
  }

  float di = dinv[row];
  unsigned* outp = (unsigned*)(h2b + (size_t)row * DIM_H + j0);
#pragma unroll
  for (int p = 0; p < 8; ++p) {
    unsigned lo = f2bf(di * acc[2 * p]);
    unsigned hi = f2bf(di * acc[2 * p + 1]);
    outp[p] = lo | (hi << 16);
  }
}

// ---------- agg2 slot-gather with index prefetch + bias + fused log_softmax ----------
__global__ __launch_bounds__(256) void k_agg2_gather(const unsigned short* __restrict__ h2b,
                                                     const float* __restrict__ dinv,
                                                     const float* __restrict__ b2,
                                                     const int* __restrict__ row_start,
                                                     const int* __restrict__ cnt,
                                                     const int* __restrict__ sorted_src,
                                                     float* __restrict__ out) {
  __shared__ float red[4][8][72];             // [wave][slot][channel], padded
  const int wv   = threadIdx.x >> 6;
  const int n    = blockIdx.x * 4 + wv;       // grid exact
  const int lane = threadIdx.x & 63;
  const int slot = lane >> 3, grp = lane & 7;
  const int start = row_start[n];
  const int deg   = cnt[n];
  const int rounds = (deg + 8) >> 3;

  float p0 = 0.f, p1 = 0.f, p2 = 0.f, p3 = 0.f, p4 = 0.f, p5 = 0.f, p6 = 0.f, p7 = 0.f;
  int row0 = (slot == 0) ? n : ((slot <= deg) ? sorted_src[start + slot - 1] : N_NODES);
  int idxn = (8 + slot <= deg) ? sorted_src[start + 8 + slot - 1] : N_NODES;  // round-1 idx
  uint4 q = *((const uint4*)(h2b + (size_t)row0 * DIM_H) + grp);
  for (int r = 1; r < rounds; ++r) {
    int row = idxn;
    int kn = (r + 1) * 8 + slot;              // prefetch round r+1's index
    idxn = (kn <= deg) ? sorted_src[start + kn - 1] : N_NODES;
    uint4 qn = *((const uint4*)(h2b + (size_t)row * DIM_H) + grp);
    p0 += blo(q.x); p1 += bhi(q.x); p2 += blo(q.y); p3 += bhi(q.y);
    p4 += blo(q.z); p5 += bhi(q.z); p6 += blo(q.w); p7 += bhi(q.w);
    q = qn;
  }
  p0 += blo(q.x); p1 += bhi(q.x); p2 += blo(q.y); p3 += bhi(q.y);
  p4 += blo(q.z); p5 += bhi(q.z); p6 += blo(q.w); p7 += bhi(q.w);

  float* rs = &red[wv][slot][grp * 8];
  rs[0] = p0; rs[1] = p1; rs[2] = p2; rs[3] = p3;
  rs[4] = p4; rs[5] = p5; rs[6] = p6; rs[7] = p7;
  __syncthreads();
  float v = 0.f;
#pragma unroll
  for (int s = 0; s < 8; ++s) v += red[wv][s][lane];

  float val = (lane < DIM_C) ? (dinv[n] * v + b2[lane]) : -INFINITY;

  // fused log_softmax over the 47 classes
  float m = val;
  for (int o = 32; o; o >>= 1) m = fmaxf(m, __shfl_xor(m, o));
  float ex = (lane < DIM_C) ? __expf(val - m) : 0.0f;
  float s = ex;
  for (int o = 32; o; o >>= 1) s += __shfl_xor(s, o);
  if (lane < DIM_C) out[(size_t)n * DIM_C + lane] = val - m - __logf(s);
}

extern "C" void kernel_launch(void* const* d_in, const int* in_sizes, int n_in,
                              void* d_out, int out_size, void* d_ws, size_t ws_size,
                              hipStream_t stream) {
  const float* x  = (const float*)d_in[0];
  const float* W1 = (const float*)d_in[1];
  const float* b1 = (const float*)d_in[2];
  const float* W2 = (const float*)d_in[3];
  const float* b2 = (const float*)d_in[4];
  const int*   ei = (const int*)d_in[5];
  const int* src = ei;
  const int* dst = ei + N_EDGES;
  float* out = (float*)d_out;

  float* ws   = (float*)d_ws;
  float* dinv = ws;                                   // N floats
  float* W2p  = dinv + N_NODES;                       // 64*48 floats
  short* W1f  = (short*)(W2p + DIM_H * DIM_CP);       // 16384 shorts
  unsigned short* h1b = (unsigned short*)(W1f + 16384);      // (N+1)*64 bf16 (sentinel row)
  float* agg1 = (float*)(h1b + (size_t)(N_NODES + 1) * DIM_H);  // N*64 f32
  unsigned short* h2b = h1b;                          // alias: h1b dead after agg1_gather
  unsigned* chunk_buf = (unsigned*)h1b;               // alias: dead before gemm1 writes h1b
  int* ibuf        = (int*)(agg1 + (size_t)N_NODES * DIM_H);
  int* cnt         = ibuf;                            // N
  int* row_start   = cnt + N_NODES;                   // N
  int* bucket_cur  = row_start + N_NODES;             // 8 (+pad)
  int* chunk_cur   = bucket_cur + 64;                 // 400
  int* chunk_base  = chunk_cur + NCHUNK;              // 400 (+pad)
  int* sorted_src  = chunk_base + NCHUNK + 64;        // E
  unsigned* bucket_buf = (unsigned*)(sorted_src + N_EDGES);  // NB*BCAP

  const int nblk_n  = (N_NODES + 255) / 256;
  const int nblk_nw = (N_NODES + 3) / 4;              // wave-per-node gathers
  const int nblk_g1 = (N_NODES + 63) / 64;            // 64-row MFMA tiles
  const int nblk_g2 = (N_NODES + 63) / 64;            // gemm2 tiles
  const int nblk_p1 = (N_EDGES + CHUNK_P1 - 1) / CHUNK_P1;   // 1563

  // CSR build: coarse bin -> fine bin -> 400-elem scan -> per-chunk LDS sort
  k_zero<<<1, 512, 0, stream>>>(bucket_cur, chunk_cur);
  k_bin<<<nblk_p1, 256, 0, stream>>>(src, dst, bucket_cur, bucket_buf);
  k_bin2<<<NB * NSEG_P2, 256, 0, stream>>>(bucket_buf, bucket_cur, chunk_cur, chunk_buf);
  k_scan_chunks<<<1, 512, 0, stream>>>(chunk_cur, chunk_base);
  k_sort_chunk<<<NCHUNK, 256, 0, stream>>>(chunk_buf, chunk_cur, chunk_base,
                                           cnt, row_start, sorted_src);
  k_dinv<<<nblk_n, 256, 0, stream>>>(cnt, dinv);
  k_padW2<<<(DIM_H * DIM_CP + 255) / 256, 256, 0, stream>>>(W2, W2p);
  k_prepW1<<<64, 256, 0, stream>>>(W1, W1f);
  k_zrow<<<1, 64, 0, stream>>>(h1b);                  // zero sentinel (chunk_buf dead by now)

  // layer 1 (MFMA, bf16 LDS tile, bf16 output) + slot-gather agg1 (f32 out)
  k_gemm1<<<nblk_g1, 256, 0, stream>>>(x, W1f, dinv, h1b);
  k_agg1_gather<<<nblk_nw, 256, 0, stream>>>(h1b, dinv, b1, row_start, cnt, sorted_src, agg1);

  // layer 2 (64-ch bf16 rows) + slot-gather agg2 + fused log_softmax
  k_gemm2<<<nblk_g2, 192, 0, stream>>>(agg1, W2p, dinv, h2b);
  k_agg2_gather<<<nblk_nw, 256, 0, stream>>>(h2b, dinv, b2, row_start, cnt, sorted_src, out);
}

// Round 23
// 200.087 us; speedup vs baseline: 1.5800x; 1.0327x over previous
//
#include <hip/hip_runtime.h>
#include <math.h>

#define N_NODES 100000
#define N_EDGES 1600000
#define DIM_IN  256
#define DIM_H   64
#define DIM_C   47
#define DIM_CP  48                            // W2p column count (padded 47->48)
#define NB       8                            // coarse dst buckets
#define BUCKET_W 12500                        // nodes per bucket
#define BCAP     204000                       // per-bucket capacity (9.5 sigma)
#define CHUNK_P1 1024                         // edges per pass-1 block (4/thread)
#define SEG_P2   2048                         // bucket-buf segment per pass-2a block
#define NSEG_P2  100                          // segments per bucket
#define CHUNK_NODES 250                       // nodes per fine chunk
#define NCHUNK   400                          // N_NODES / 250
#define CCAP     4608                         // per-chunk edge capacity
#define XBP      264                          // bf16 x-tile row stride (+8 pad)

typedef __attribute__((ext_vector_type(8))) short bf16x8;
typedef __attribute__((ext_vector_type(4))) float f32x4;

// RNE float -> bf16 bits
static __device__ __forceinline__ unsigned short f2bf(float f) {
  unsigned u = __builtin_bit_cast(unsigned, f);
  u += 0x7FFFu + ((u >> 16) & 1u);
  return (unsigned short)(u >> 16);
}
static __device__ __forceinline__ float bf2f(unsigned short h) {
  unsigned u = ((unsigned)h) << 16;
  return __builtin_bit_cast(float, u);
}
static __device__ __forceinline__ float blo(unsigned u) {
  return __builtin_bit_cast(float, u << 16);
}
static __device__ __forceinline__ float bhi(unsigned u) {
  return __builtin_bit_cast(float, u & 0xffff0000u);
}

// ---------- fused prep: counter zero + W2 pad + W1 fragment swizzle ----------
__global__ __launch_bounds__(256) void k_prep(int* __restrict__ bucket_cur,
                                              int* __restrict__ chunk_cur,
                                              const float* __restrict__ W2,
                                              float* __restrict__ W2p,
                                              const float* __restrict__ W1,
                                              short* __restrict__ W1f) {
  int i = blockIdx.x * 256 + threadIdx.x;
  if (i < NB) bucket_cur[i] = 0;
  if (i < NCHUNK) chunk_cur[i] = 0;
  if (i < DIM_H * DIM_CP) {                   // W2 pad (3072)
    int k = i / DIM_CP, j = i % DIM_CP;
    W2p[i] = (j < DIM_C) ? W2[k * DIM_C + j] : 0.f;
  }
  if (i < 4 * 8 * 64 * 8) {                   // W1 fragment swizzle (16384)
    int e    = i & 7;
    int lane = (i >> 3) & 63;
    int ks   = (i >> 9) & 7;
    int wv   = i >> 12;
    int col  = wv * 16 + (lane & 15);
    int k    = ks * 32 + (lane >> 4) * 8 + e;
    W1f[i] = (short)f2bf(W1[k * DIM_H + col]);
  }
}

// ---------- pass 1: coarse octant binning (dense reservation writes) ----------
__global__ __launch_bounds__(256) void k_bin(const int* __restrict__ src,
                                             const int* __restrict__ dst,
                                             int* __restrict__ bucket_cur,
                                             unsigned* __restrict__ bucket_buf) {
  __shared__ int lcnt[NB], lbase[NB], lcur[NB];
  if (threadIdx.x < NB) lcnt[threadIdx.x] = 0;
  __syncthreads();
  const int base = blockIdx.x * CHUNK_P1 + threadIdx.x;
  int dreg[4], sreg[4];
#pragma unroll
  for (int it = 0; it < 4; ++it) {
    int e = base + it * 256;
    int d = -1, s = 0;
    if (e < N_EDGES) { d = dst[e]; s = src[e]; }
    dreg[it] = d; sreg[it] = s;
    if (d >= 0) atomicAdd(&lcnt[d / BUCKET_W], 1);
  }
  __syncthreads();
  if (threadIdx.x < NB) {
    lbase[threadIdx.x] = atomicAdd(&bucket_cur[threadIdx.x], lcnt[threadIdx.x]);
    lcur[threadIdx.x] = 0;
  }
  __syncthreads();
#pragma unroll
  for (int it = 0; it < 4; ++it) {
    int d = dreg[it];
    if (d >= 0) {
      int b = d / BUCKET_W;
      int r = atomicAdd(&lcur[b], 1);
      unsigned pack = ((unsigned)(d - b * BUCKET_W) << 17) | (unsigned)sreg[it];
      bucket_buf[(size_t)b * BCAP + lbase[b] + r] = pack;
    }
  }
}

// ---------- pass 2a: bucket -> 50 fine chunks (dense reservation writes) ----------
__global__ __launch_bounds__(256) void k_bin2(const unsigned* __restrict__ bucket_buf,
                                              const int* __restrict__ bucket_cnt,
                                              int* __restrict__ chunk_cur,
                                              unsigned* __restrict__ chunk_buf) {
  const int b   = blockIdx.x / NSEG_P2;
  const int seg = blockIdx.x % NSEG_P2;
  const int n_b = bucket_cnt[b];
  const int s0  = seg * SEG_P2;
  const int s1  = (n_b < s0 + SEG_P2) ? n_b : (s0 + SEG_P2);
  __shared__ int lcnt[50], lbase[50], lcur[50];
  if (threadIdx.x < 50) lcnt[threadIdx.x] = 0;
  __syncthreads();
  unsigned preg[8]; int creg[8];
#pragma unroll
  for (int it = 0; it < 8; ++it) {
    int i = s0 + it * 256 + (int)threadIdx.x;
    unsigned p = 0; int cl = -1;
    if (i < s1) { p = bucket_buf[(size_t)b * BCAP + i]; cl = (int)(p >> 17) / CHUNK_NODES; atomicAdd(&lcnt[cl], 1); }
    preg[it] = p; creg[it] = cl;
  }
  __syncthreads();
  if (threadIdx.x < 50) {
    lbase[threadIdx.x] = atomicAdd(&chunk_cur[b * 50 + threadIdx.x], lcnt[threadIdx.x]);
    lcur[threadIdx.x] = 0;
  }
  __syncthreads();
#pragma unroll
  for (int it = 0; it < 8; ++it) {
    int cl = creg[it];
    if (cl >= 0) {
      unsigned p = preg[it];
      int dl = (int)(p >> 17) - cl * CHUNK_NODES;   // 0..249 within chunk
      int r = atomicAdd(&lcur[cl], 1);
      chunk_buf[(size_t)(b * 50 + cl) * CCAP + lbase[cl] + r] =
          ((unsigned)dl << 17) | (p & 0x1FFFFu);
    }
  }
}

// ---------- exclusive scan of the 400 chunk counts ----------
__global__ __launch_bounds__(512) void k_scan_chunks(const int* __restrict__ chunk_cur,
                                                     int* __restrict__ chunk_base) {
  __shared__ int ls[512];
  const int tid = threadIdx.x;
  int v = (tid < NCHUNK) ? chunk_cur[tid] : 0;
  ls[tid] = v;
  __syncthreads();
  for (int off = 1; off < 512; off <<= 1) {
    int u = (tid >= off) ? ls[tid - off] : 0;
    __syncthreads();
    ls[tid] += u;
    __syncthreads();
  }
  if (tid < NCHUNK) chunk_base[tid] = ls[tid] - v;
}

// ---------- pass 2b: per-chunk LDS counting sort; sequential global writes ----------
__global__ __launch_bounds__(256) void k_sort_chunk(const unsigned* __restrict__ chunk_buf,
                                                    const int* __restrict__ chunk_cur,
                                                    const int* __restrict__ chunk_base,
                                                    int* __restrict__ cnt,
                                                    int* __restrict__ row_start,
                                                    int* __restrict__ sorted_src) {
  const int c    = blockIdx.x;
  const int n_c  = chunk_cur[c];
  const int base = chunk_base[c];
  const unsigned* buf = chunk_buf + (size_t)c * CCAP;
  __shared__ int cntA[256], exclA[256], curA[256];
  __shared__ int sortedL[CCAP];
  const int tid = threadIdx.x;
  cntA[tid] = 0; curA[tid] = 0;
  __syncthreads();
  for (int i = tid; i < n_c; i += 256) atomicAdd(&cntA[buf[i] >> 17], 1);
  __syncthreads();
  int myc = cntA[tid];
  exclA[tid] = myc;
  __syncthreads();
  for (int off = 1; off < 256; off <<= 1) {
    int u = (tid >= off) ? exclA[tid - off] : 0;
    __syncthreads();
    exclA[tid] += u;
    __syncthreads();
  }
  int excl = exclA[tid] - myc;
  if (tid < CHUNK_NODES) {
    int n = c * CHUNK_NODES + tid;
    cnt[n] = myc;
    row_start[n] = base + excl;
  }
  __syncthreads();
  exclA[tid] = excl;
  __syncthreads();
  for (int i = tid; i < n_c; i += 256) {
    unsigned p = buf[i];
    int dl = (int)(p >> 17);
    int pos = exclA[dl] + atomicAdd(&curA[dl], 1);
    sortedL[pos] = (int)(p & 0x1FFFFu);
  }
  __syncthreads();
  for (int i = tid; i < n_c; i += 256) sorted_src[base + i] = sortedL[i];
}

// ---------- dinv = rsqrt(deg+1) + zero sentinel row (fused) ----------
__global__ __launch_bounds__(256) void k_dinv(const int* __restrict__ cnt,
                                              float* __restrict__ dinv,
                                              unsigned short* __restrict__ h1b) {
  int i = blockIdx.x * 256 + threadIdx.x;
  if (i < N_NODES) dinv[i] = rsqrtf((float)cnt[i] + 1.0f);
  if (i < DIM_H) h1b[(size_t)N_NODES * DIM_H + i] = 0;   // sentinel row
}

// ---------- layer 1 GEMM on matrix cores: h1b = bf16(dinv[n] * (x @ W1)) ----------
__global__ __launch_bounds__(256) void k_gemm1(const float* __restrict__ x,
                                               const short* __restrict__ W1f,
                                               const float* __restrict__ dinv,
                                               unsigned short* __restrict__ h1b) {
  __shared__ unsigned short xb[64][XBP];      // 33792B
  const int lane = threadIdx.x & 63;
  const int wv   = threadIdx.x >> 6;
  const int m16  = lane & 15;
  const int kb   = lane >> 4;                 // 0..3
  const int base_row = blockIdx.x * 64;

#pragma unroll 4
  for (int i = 0; i < 16; ++i) {
    int r = i * 4 + wv;
    int grow = base_row + r;
    if (grow >= N_NODES) grow = N_NODES - 1;
    float4 v = *(const float4*)(x + (size_t)grow * DIM_IN + lane * 4);
    ushort4 b;
    b.x = f2bf(v.x); b.y = f2bf(v.y); b.z = f2bf(v.z); b.w = f2bf(v.w);
    *(ushort4*)&xb[r][lane * 4] = b;
  }
  __syncthreads();

  const bf16x8* wf = (const bf16x8*)W1f + (size_t)wv * 8 * 64 + lane;
  f32x4 c0 = {0.f, 0.f, 0.f, 0.f}, c1 = c0, c2 = c0, c3 = c0;
#pragma unroll
  for (int ks = 0; ks < 8; ++ks) {
    bf16x8 bb = wf[ks * 64];
#pragma unroll
    for (int rg = 0; rg < 4; ++rg) {
      bf16x8 af = *(const bf16x8*)&xb[rg * 16 + m16][ks * 32 + kb * 8];
      if (rg == 0) c0 = __builtin_amdgcn_mfma_f32_16x16x32_bf16(af, bb, c0, 0, 0, 0);
      if (rg == 1) c1 = __builtin_amdgcn_mfma_f32_16x16x32_bf16(af, bb, c1, 0, 0, 0);
      if (rg == 2) c2 = __builtin_amdgcn_mfma_f32_16x16x32_bf16(af, bb, c2, 0, 0, 0);
      if (rg == 3) c3 = __builtin_amdgcn_mfma_f32_16x16x32_bf16(af, bb, c3, 0, 0, 0);
    }
  }

  const int j0 = wv * 16 + m16;               // output column
#pragma unroll
  for (int rg = 0; rg < 4; ++rg) {
    f32x4 c = (rg == 0) ? c0 : (rg == 1) ? c1 : (rg == 2) ? c2 : c3;
#pragma unroll
    for (int r = 0; r < 4; ++r) {
      int row = base_row + rg * 16 + kb * 4 + r;
      if (row < N_NODES) h1b[(size_t)row * DIM_H + j0] = f2bf(c[r] * dinv[row]);
    }
  }
}

// ---------- agg1 slot-gather + fused bias/ReLU -> bf16 A1 ----------
__global__ __launch_bounds__(256) void k_agg1_gather(const unsigned short* __restrict__ h1b,
                                                     const float* __restrict__ dinv,
                                                     const float* __restrict__ b1,
                                                     const int* __restrict__ row_start,
                                                     const int* __restrict__ cnt,
                                                     const int* __restrict__ sorted_src,
                                                     unsigned short* __restrict__ A1) {
  __shared__ float red[4][8][72];             // [wave][slot][channel], padded
  const int wv   = threadIdx.x >> 6;
  const int n    = blockIdx.x * 4 + wv;       // grid exact: 25000*4 == N_NODES
  const int lane = threadIdx.x & 63;
  const int slot = lane >> 3, grp = lane & 7;
  const int start = row_start[n];
  const int deg   = cnt[n];
  const int rounds = (deg + 8) >> 3;          // ceil((deg+1)/8)

  float p0 = 0.f, p1 = 0.f, p2 = 0.f, p3 = 0.f, p4 = 0.f, p5 = 0.f, p6 = 0.f, p7 = 0.f;
  int row0 = (slot == 0) ? n : ((slot <= deg) ? sorted_src[start + slot - 1] : N_NODES);
  int idxn = (8 + slot <= deg) ? sorted_src[start + 8 + slot - 1] : N_NODES;
  uint4 q = *((const uint4*)(h1b + (size_t)row0 * DIM_H) + grp);
  for (int r = 1; r < rounds; ++r) {
    int row = idxn;
    int kn = (r + 1) * 8 + slot;              // prefetch round r+1's index
    idxn = (kn <= deg) ? sorted_src[start + kn - 1] : N_NODES;
    uint4 qn = *((const uint4*)(h1b + (size_t)row * DIM_H) + grp);
    p0 += blo(q.x); p1 += bhi(q.x); p2 += blo(q.y); p3 += bhi(q.y);
    p4 += blo(q.z); p5 += bhi(q.z); p6 += blo(q.w); p7 += bhi(q.w);
    q = qn;
  }
  p0 += blo(q.x); p1 += bhi(q.x); p2 += blo(q.y); p3 += bhi(q.y);
  p4 += blo(q.z); p5 += bhi(q.z); p6 += blo(q.w); p7 += bhi(q.w);

  float* rs = &red[wv][slot][grp * 8];
  rs[0] = p0; rs[1] = p1; rs[2] = p2; rs[3] = p3;
  rs[4] = p4; rs[5] = p5; rs[6] = p6; rs[7] = p7;
  __syncthreads();
  float v = 0.f;
#pragma unroll
  for (int s = 0; s < 8; ++s) v += red[wv][s][lane];
  float H1 = dinv[n] * v + b1[lane];
  A1[(size_t)n * DIM_H + lane] = f2bf(fmaxf(H1, 0.f));
}

// ---------- layer 2 GEMM (bf16 in, ReLU pre-applied): h2b = bf16(dinv*(A1@W2p)) ----------
// FIX vs R17/R21: a 64-ch bf16 row is 8 uint4 (not 4); loop d=0..31 covers all
// K=64 (the failed rounds silently dropped channels 32..63).
__global__ __launch_bounds__(192) void k_gemm2(const unsigned short* __restrict__ A1,
                                               const float* __restrict__ W2p,
                                               const float* __restrict__ dinv,
                                               unsigned short* __restrict__ h2b) {
  const int lane = threadIdx.x & 63;
  const int j0   = __builtin_amdgcn_readfirstlane((threadIdx.x >> 6) * 16);
  int row = blockIdx.x * 64 + lane;
  if (row >= N_NODES) row = N_NODES - 1;
  const uint4* ar = (const uint4*)(A1 + (size_t)row * DIM_H);
  uint4 av[8];
#pragma unroll
  for (int t = 0; t < 8; ++t) av[t] = ar[t];
  __builtin_amdgcn_sched_barrier(0);

  float acc[16];
#pragma unroll
  for (int j = 0; j < 16; ++j) acc[j] = 0.f;

#pragma unroll
  for (int t = 0; t < 8; ++t) {
    unsigned d4[4] = {av[t].x, av[t].y, av[t].z, av[t].w};
#pragma unroll
    for (int u = 0; u < 4; ++u) {
      int d = t * 4 + u;                      // dword index 0..31 -> channels 2d, 2d+1
      float x0 = blo(d4[u]), x1 = bhi(d4[u]);
      const float* w0 = W2p + (size_t)(2 * d) * DIM_CP + j0;      // uniform -> s_load
      const float* w1 = W2p + (size_t)(2 * d + 1) * DIM_CP + j0;
#pragma unroll
      for (int j = 0; j < 16; ++j) {
        acc[j] = fmaf(x0, w0[j], acc[j]);
        acc[j] = fmaf(x1, w1[j], acc[j]);
      }
    }
  }

  float di = dinv[row];
  unsigned* outp = (unsigned*)(h2b + (size_t)row * DIM_H + j0);
#pragma unroll
  for (int p = 0; p < 8; ++p) {
    unsigned lo = f2bf(di * acc[2 * p]);
    unsigned hi = f2bf(di * acc[2 * p + 1]);
    outp[p] = lo | (hi << 16);
  }
}

// ---------- agg2 slot-gather with index prefetch + bias + fused log_softmax ----------
__global__ __launch_bounds__(256) void k_agg2_gather(const unsigned short* __restrict__ h2b,
                                                     const float* __restrict__ dinv,
                                                     const float* __restrict__ b2,
                                                     const int* __restrict__ row_start,
                                                     const int* __restrict__ cnt,
                                                     const int* __restrict__ sorted_src,
                                                     float* __restrict__ out) {
  __shared__ float red[4][8][72];             // [wave][slot][channel], padded
  const int wv   = threadIdx.x >> 6;
  const int n    = blockIdx.x * 4 + wv;       // grid exact
  const int lane = threadIdx.x & 63;
  const int slot = lane >> 3, grp = lane & 7;
  const int start = row_start[n];
  const int deg   = cnt[n];
  const int rounds = (deg + 8) >> 3;

  float p0 = 0.f, p1 = 0.f, p2 = 0.f, p3 = 0.f, p4 = 0.f, p5 = 0.f, p6 = 0.f, p7 = 0.f;
  int row0 = (slot == 0) ? n : ((slot <= deg) ? sorted_src[start + slot - 1] : N_NODES);
  int idxn = (8 + slot <= deg) ? sorted_src[start + 8 + slot - 1] : N_NODES;
  uint4 q = *((const uint4*)(h2b + (size_t)row0 * DIM_H) + grp);
  for (int r = 1; r < rounds; ++r) {
    int row = idxn;
    int kn = (r + 1) * 8 + slot;              // prefetch round r+1's index
    idxn = (kn <= deg) ? sorted_src[start + kn - 1] : N_NODES;
    uint4 qn = *((const uint4*)(h2b + (size_t)row * DIM_H) + grp);
    p0 += blo(q.x); p1 += bhi(q.x); p2 += blo(q.y); p3 += bhi(q.y);
    p4 += blo(q.z); p5 += bhi(q.z); p6 += blo(q.w); p7 += bhi(q.w);
    q = qn;
  }
  p0 += blo(q.x); p1 += bhi(q.x); p2 += blo(q.y); p3 += bhi(q.y);
  p4 += blo(q.z); p5 += bhi(q.z); p6 += blo(q.w); p7 += bhi(q.w);

  float* rs = &red[wv][slot][grp * 8];
  rs[0] = p0; rs[1] = p1; rs[2] = p2; rs[3] = p3;
  rs[4] = p4; rs[5] = p5; rs[6] = p6; rs[7] = p7;
  __syncthreads();
  float v = 0.f;
#pragma unroll
  for (int s = 0; s < 8; ++s) v += red[wv][s][lane];

  float val = (lane < DIM_C) ? (dinv[n] * v + b2[lane]) : -INFINITY;

  // fused log_softmax over the 47 classes
  float m = val;
  for (int o = 32; o; o >>= 1) m = fmaxf(m, __shfl_xor(m, o));
  float ex = (lane < DIM_C) ? __expf(val - m) : 0.0f;
  float s = ex;
  for (int o = 32; o; o >>= 1) s += __shfl_xor(s, o);
  if (lane < DIM_C) out[(size_t)n * DIM_C + lane] = val - m - __logf(s);
}

extern "C" void kernel_launch(void* const* d_in, const int* in_sizes, int n_in,
                              void* d_out, int out_size, void* d_ws, size_t ws_size,
                              hipStream_t stream) {
  const float* x  = (const float*)d_in[0];
  const float* W1 = (const float*)d_in[1];
  const float* b1 = (const float*)d_in[2];
  const float* W2 = (const float*)d_in[3];
  const float* b2 = (const float*)d_in[4];
  const int*   ei = (const int*)d_in[5];
  const int* src = ei;
  const int* dst = ei + N_EDGES;
  float* out = (float*)d_out;

  float* ws   = (float*)d_ws;
  float* dinv = ws;                                   // N floats
  float* W2p  = dinv + N_NODES;                       // 64*48 floats
  short* W1f  = (short*)(W2p + DIM_H * DIM_CP);       // 16384 shorts
  unsigned short* h1b = (unsigned short*)(W1f + 16384);      // (N+1)*64 bf16 (sentinel row)
  unsigned short* A1  = h1b + (size_t)(N_NODES + 1) * DIM_H; // N*64 bf16
  unsigned short* h2b = h1b;                          // alias: h1b dead after agg1_gather
  unsigned* chunk_buf = (unsigned*)h1b;               // alias: dead before gemm1 writes h1b
  int* ibuf        = (int*)(A1 + (size_t)N_NODES * DIM_H);
  int* cnt         = ibuf;                            // N
  int* row_start   = cnt + N_NODES;                   // N
  int* bucket_cur  = row_start + N_NODES;             // 8 (+pad)
  int* chunk_cur   = bucket_cur + 64;                 // 400
  int* chunk_base  = chunk_cur + NCHUNK;              // 400 (+pad)
  int* sorted_src  = chunk_base + NCHUNK + 64;        // E
  unsigned* bucket_buf = (unsigned*)(sorted_src + N_EDGES);  // NB*BCAP

  const int nblk_n  = (N_NODES + 255) / 256;
  const int nblk_nw = (N_NODES + 3) / 4;              // wave-per-node gathers
  const int nblk_g1 = (N_NODES + 63) / 64;            // 64-row MFMA tiles
  const int nblk_g2 = (N_NODES + 63) / 64;            // gemm2 tiles
  const int nblk_p1 = (N_EDGES + CHUNK_P1 - 1) / CHUNK_P1;   // 1563

  // fused prep (counters + W2 pad + W1 swizzle), then CSR build
  k_prep<<<64, 256, 0, stream>>>(bucket_cur, chunk_cur, W2, W2p, W1, W1f);
  k_bin<<<nblk_p1, 256, 0, stream>>>(src, dst, bucket_cur, bucket_buf);
  k_bin2<<<NB * NSEG_P2, 256, 0, stream>>>(bucket_buf, bucket_cur, chunk_cur, chunk_buf);
  k_scan_chunks<<<1, 512, 0, stream>>>(chunk_cur, chunk_base);
  k_sort_chunk<<<NCHUNK, 256, 0, stream>>>(chunk_buf, chunk_cur, chunk_base,
                                           cnt, row_start, sorted_src);
  k_dinv<<<nblk_n, 256, 0, stream>>>(cnt, dinv, h1b);   // + sentinel zero (chunk_buf dead)

  // layer 1 (MFMA, bf16 LDS tile, bf16 output) + slot-gather agg1 -> bf16 A1
  k_gemm1<<<nblk_g1, 256, 0, stream>>>(x, W1f, dinv, h1b);
  k_agg1_gather<<<nblk_nw, 256, 0, stream>>>(h1b, dinv, b1, row_start, cnt, sorted_src, A1);

  // layer 2 (bf16 in, 64-ch bf16 rows out) + slot-gather agg2 + fused log_softmax
  k_gemm2<<<nblk_g2, 192, 0, stream>>>(A1, W2p, dinv, h2b);
  k_agg2_gather<<<nblk_nw, 256, 0, stream>>>(h2b, dinv, b2, row_start, cnt, sorted_src, out);
}

// Round 24
// 190.027 us; speedup vs baseline: 1.6636x; 1.0529x over previous
//
#include <hip/hip_runtime.h>
#include <math.h>

#define N_NODES 100000
#define N_EDGES 1600000
#define DIM_IN  256
#define DIM_H   64
#define DIM_C   47
#define DIM_CP  48                            // W2p column count (padded 47->48)
#define NB       8                            // coarse dst buckets
#define BUCKET_W 12500                        // nodes per bucket
#define BCAP     204000                       // per-bucket capacity (9.5 sigma)
#define CHUNK_P1 2048                         // edges per pass-1 block (8/thread)
#define SEG_P2   2048                         // bucket-buf segment per pass-2a block
#define NSEG_P2  100                          // segments per bucket
#define CHUNK_NODES 250                       // nodes per fine chunk
#define NCHUNK   400                          // N_NODES / 250
#define CCAP     4608                         // per-chunk edge capacity
#define XBP      264                          // bf16 x-tile row stride (+8 pad)

typedef __attribute__((ext_vector_type(8))) short bf16x8;
typedef __attribute__((ext_vector_type(4))) float f32x4;

// RNE float -> bf16 bits
static __device__ __forceinline__ unsigned short f2bf(float f) {
  unsigned u = __builtin_bit_cast(unsigned, f);
  u += 0x7FFFu + ((u >> 16) & 1u);
  return (unsigned short)(u >> 16);
}
static __device__ __forceinline__ float bf2f(unsigned short h) {
  unsigned u = ((unsigned)h) << 16;
  return __builtin_bit_cast(float, u);
}
static __device__ __forceinline__ float blo(unsigned u) {
  return __builtin_bit_cast(float, u << 16);
}
static __device__ __forceinline__ float bhi(unsigned u) {
  return __builtin_bit_cast(float, u & 0xffff0000u);
}

// ---------- fused prep: counters + W2 pad + W1 swizzle + h1b sentinel zero ----------
// Sentinel (h1b row N, byte offset 12.8MB) is beyond chunk_buf's 7.4MB aliased
// extent, so bin2/sort never overwrite it.
__global__ __launch_bounds__(256) void k_prep(int* __restrict__ bucket_cur,
                                              int* __restrict__ chunk_cur,
                                              const float* __restrict__ W2,
                                              float* __restrict__ W2p,
                                              const float* __restrict__ W1,
                                              short* __restrict__ W1f,
                                              unsigned short* __restrict__ h1b) {
  int i = blockIdx.x * 256 + threadIdx.x;
  if (i < NB) bucket_cur[i] = 0;
  if (i < NCHUNK) chunk_cur[i] = 0;
  if (i < DIM_H) h1b[(size_t)N_NODES * DIM_H + i] = 0;   // sentinel row
  if (i < DIM_H * DIM_CP) {                   // W2 pad (3072)
    int k = i / DIM_CP, j = i % DIM_CP;
    W2p[i] = (j < DIM_C) ? W2[k * DIM_C + j] : 0.f;
  }
  if (i < 4 * 8 * 64 * 8) {                   // W1 fragment swizzle (16384)
    int e    = i & 7;
    int lane = (i >> 3) & 63;
    int ks   = (i >> 9) & 7;
    int wv   = i >> 12;
    int col  = wv * 16 + (lane & 15);
    int k    = ks * 32 + (lane >> 4) * 8 + e;
    W1f[i] = (short)f2bf(W1[k * DIM_H + col]);
  }
}

// ---------- pass 1: coarse octant binning (dense reservation writes) ----------
__global__ __launch_bounds__(256) void k_bin(const int* __restrict__ src,
                                             const int* __restrict__ dst,
                                             int* __restrict__ bucket_cur,
                                             unsigned* __restrict__ bucket_buf) {
  __shared__ int lcnt[NB], lbase[NB], lcur[NB];
  if (threadIdx.x < NB) lcnt[threadIdx.x] = 0;
  __syncthreads();
  const int base = blockIdx.x * CHUNK_P1 + threadIdx.x;
  int dreg[8], sreg[8];
#pragma unroll
  for (int it = 0; it < 8; ++it) {
    int e = base + it * 256;
    int d = -1, s = 0;
    if (e < N_EDGES) { d = dst[e]; s = src[e]; }
    dreg[it] = d; sreg[it] = s;
    if (d >= 0) atomicAdd(&lcnt[d / BUCKET_W], 1);
  }
  __syncthreads();
  if (threadIdx.x < NB) {
    lbase[threadIdx.x] = atomicAdd(&bucket_cur[threadIdx.x], lcnt[threadIdx.x]);
    lcur[threadIdx.x] = 0;
  }
  __syncthreads();
#pragma unroll
  for (int it = 0; it < 8; ++it) {
    int d = dreg[it];
    if (d >= 0) {
      int b = d / BUCKET_W;
      int r = atomicAdd(&lcur[b], 1);
      unsigned pack = ((unsigned)(d - b * BUCKET_W) << 17) | (unsigned)sreg[it];
      bucket_buf[(size_t)b * BCAP + lbase[b] + r] = pack;
    }
  }
}

// ---------- pass 2a: bucket -> 50 fine chunks (dense reservation writes) ----------
__global__ __launch_bounds__(256) void k_bin2(const unsigned* __restrict__ bucket_buf,
                                              const int* __restrict__ bucket_cnt,
                                              int* __restrict__ chunk_cur,
                                              unsigned* __restrict__ chunk_buf) {
  const int b   = blockIdx.x / NSEG_P2;
  const int seg = blockIdx.x % NSEG_P2;
  const int n_b = bucket_cnt[b];
  const int s0  = seg * SEG_P2;
  const int s1  = (n_b < s0 + SEG_P2) ? n_b : (s0 + SEG_P2);
  __shared__ int lcnt[50], lbase[50], lcur[50];
  if (threadIdx.x < 50) lcnt[threadIdx.x] = 0;
  __syncthreads();
  unsigned preg[8]; int creg[8];
#pragma unroll
  for (int it = 0; it < 8; ++it) {
    int i = s0 + it * 256 + (int)threadIdx.x;
    unsigned p = 0; int cl = -1;
    if (i < s1) { p = bucket_buf[(size_t)b * BCAP + i]; cl = (int)(p >> 17) / CHUNK_NODES; atomicAdd(&lcnt[cl], 1); }
    preg[it] = p; creg[it] = cl;
  }
  __syncthreads();
  if (threadIdx.x < 50) {
    lbase[threadIdx.x] = atomicAdd(&chunk_cur[b * 50 + threadIdx.x], lcnt[threadIdx.x]);
    lcur[threadIdx.x] = 0;
  }
  __syncthreads();
#pragma unroll
  for (int it = 0; it < 8; ++it) {
    int cl = creg[it];
    if (cl >= 0) {
      unsigned p = preg[it];
      int dl = (int)(p >> 17) - cl * CHUNK_NODES;   // 0..249 within chunk
      int r = atomicAdd(&lcur[cl], 1);
      chunk_buf[(size_t)(b * 50 + cl) * CCAP + lbase[cl] + r] =
          ((unsigned)dl << 17) | (p & 0x1FFFFu);
    }
  }
}

// ---------- exclusive scan of the 400 chunk counts ----------
__global__ __launch_bounds__(512) void k_scan_chunks(const int* __restrict__ chunk_cur,
                                                     int* __restrict__ chunk_base) {
  __shared__ int ls[512];
  const int tid = threadIdx.x;
  int v = (tid < NCHUNK) ? chunk_cur[tid] : 0;
  ls[tid] = v;
  __syncthreads();
  for (int off = 1; off < 512; off <<= 1) {
    int u = (tid >= off) ? ls[tid - off] : 0;
    __syncthreads();
    ls[tid] += u;
    __syncthreads();
  }
  if (tid < NCHUNK) chunk_base[tid] = ls[tid] - v;
}

// ---------- pass 2b: per-chunk LDS counting sort (+ fused dinv) ----------
__global__ __launch_bounds__(256) void k_sort_chunk(const unsigned* __restrict__ chunk_buf,
                                                    const int* __restrict__ chunk_cur,
                                                    const int* __restrict__ chunk_base,
                                                    int* __restrict__ cnt,
                                                    int* __restrict__ row_start,
                                                    int* __restrict__ sorted_src,
                                                    float* __restrict__ dinv) {
  const int c    = blockIdx.x;
  const int n_c  = chunk_cur[c];
  const int base = chunk_base[c];
  const unsigned* buf = chunk_buf + (size_t)c * CCAP;
  __shared__ int cntA[256], exclA[256], curA[256];
  __shared__ int sortedL[CCAP];
  const int tid = threadIdx.x;
  cntA[tid] = 0; curA[tid] = 0;
  __syncthreads();
  for (int i = tid; i < n_c; i += 256) atomicAdd(&cntA[buf[i] >> 17], 1);
  __syncthreads();
  int myc = cntA[tid];
  exclA[tid] = myc;
  __syncthreads();
  for (int off = 1; off < 256; off <<= 1) {
    int u = (tid >= off) ? exclA[tid - off] : 0;
    __syncthreads();
    exclA[tid] += u;
    __syncthreads();
  }
  int excl = exclA[tid] - myc;
  if (tid < CHUNK_NODES) {
    int n = c * CHUNK_NODES + tid;
    cnt[n] = myc;
    row_start[n] = base + excl;
    dinv[n] = rsqrtf((float)myc + 1.0f);      // fused (replaces k_dinv)
  }
  __syncthreads();
  exclA[tid] = excl;
  __syncthreads();
  for (int i = tid; i < n_c; i += 256) {
    unsigned p = buf[i];
    int dl = (int)(p >> 17);
    int pos = exclA[dl] + atomicAdd(&curA[dl], 1);
    sortedL[pos] = (int)(p & 0x1FFFFu);
  }
  __syncthreads();
  for (int i = tid; i < n_c; i += 256) sorted_src[base + i] = sortedL[i];
}

// ---------- layer 1 GEMM on matrix cores: h1b = bf16(dinv[n] * (x @ W1)) ----------
__global__ __launch_bounds__(256) void k_gemm1(const float* __restrict__ x,
                                               const short* __restrict__ W1f,
                                               const float* __restrict__ dinv,
                                               unsigned short* __restrict__ h1b) {
  __shared__ unsigned short xb[64][XBP];      // 33792B
  const int lane = threadIdx.x & 63;
  const int wv   = threadIdx.x >> 6;
  const int m16  = lane & 15;
  const int kb   = lane >> 4;                 // 0..3
  const int base_row = blockIdx.x * 64;

#pragma unroll 8
  for (int i = 0; i < 16; ++i) {
    int r = i * 4 + wv;
    int grow = base_row + r;
    if (grow >= N_NODES) grow = N_NODES - 1;
    float4 v = *(const float4*)(x + (size_t)grow * DIM_IN + lane * 4);
    ushort4 b;
    b.x = f2bf(v.x); b.y = f2bf(v.y); b.z = f2bf(v.z); b.w = f2bf(v.w);
    *(ushort4*)&xb[r][lane * 4] = b;
  }
  __syncthreads();

  const bf16x8* wf = (const bf16x8*)W1f + (size_t)wv * 8 * 64 + lane;
  f32x4 c0 = {0.f, 0.f, 0.f, 0.f}, c1 = c0, c2 = c0, c3 = c0;
#pragma unroll
  for (int ks = 0; ks < 8; ++ks) {
    bf16x8 bb = wf[ks * 64];
#pragma unroll
    for (int rg = 0; rg < 4; ++rg) {
      bf16x8 af = *(const bf16x8*)&xb[rg * 16 + m16][ks * 32 + kb * 8];
      if (rg == 0) c0 = __builtin_amdgcn_mfma_f32_16x16x32_bf16(af, bb, c0, 0, 0, 0);
      if (rg == 1) c1 = __builtin_amdgcn_mfma_f32_16x16x32_bf16(af, bb, c1, 0, 0, 0);
      if (rg == 2) c2 = __builtin_amdgcn_mfma_f32_16x16x32_bf16(af, bb, c2, 0, 0, 0);
      if (rg == 3) c3 = __builtin_amdgcn_mfma_f32_16x16x32_bf16(af, bb, c3, 0, 0, 0);
    }
  }

  const int j0 = wv * 16 + m16;               // output column
#pragma unroll
  for (int rg = 0; rg < 4; ++rg) {
    f32x4 c = (rg == 0) ? c0 : (rg == 1) ? c1 : (rg == 2) ? c2 : c3;
#pragma unroll
    for (int r = 0; r < 4; ++r) {
      int row = base_row + rg * 16 + kb * 4 + r;
      if (row < N_NODES) h1b[(size_t)row * DIM_H + j0] = f2bf(c[r] * dinv[row]);
    }
  }
}

// ---------- agg1 slot-gather + fused bias/ReLU -> bf16 A1 ----------
__global__ __launch_bounds__(256) void k_agg1_gather(const unsigned short* __restrict__ h1b,
                                                     const float* __restrict__ dinv,
                                                     const float* __restrict__ b1,
                                                     const int* __restrict__ row_start,
                                                     const int* __restrict__ cnt,
                                                     const int* __restrict__ sorted_src,
                                                     unsigned short* __restrict__ A1) {
  __shared__ float red[4][8][72];             // [wave][slot][channel], padded
  const int wv   = threadIdx.x >> 6;
  const int n    = blockIdx.x * 4 + wv;       // grid exact: 25000*4 == N_NODES
  const int lane = threadIdx.x & 63;
  const int slot = lane >> 3, grp = lane & 7;
  const int start = row_start[n];
  const int deg   = cnt[n];
  const int rounds = (deg + 8) >> 3;          // ceil((deg+1)/8)

  float p0 = 0.f, p1 = 0.f, p2 = 0.f, p3 = 0.f, p4 = 0.f, p5 = 0.f, p6 = 0.f, p7 = 0.f;
  int row0 = (slot == 0) ? n : ((slot <= deg) ? sorted_src[start + slot - 1] : N_NODES);
  int idxn = (8 + slot <= deg) ? sorted_src[start + 8 + slot - 1] : N_NODES;
  uint4 q = *((const uint4*)(h1b + (size_t)row0 * DIM_H) + grp);
  for (int r = 1; r < rounds; ++r) {
    int row = idxn;
    int kn = (r + 1) * 8 + slot;              // prefetch round r+1's index
    idxn = (kn <= deg) ? sorted_src[start + kn - 1] : N_NODES;
    uint4 qn = *((const uint4*)(h1b + (size_t)row * DIM_H) + grp);
    p0 += blo(q.x); p1 += bhi(q.x); p2 += blo(q.y); p3 += bhi(q.y);
    p4 += blo(q.z); p5 += bhi(q.z); p6 += blo(q.w); p7 += bhi(q.w);
    q = qn;
  }
  p0 += blo(q.x); p1 += bhi(q.x); p2 += blo(q.y); p3 += bhi(q.y);
  p4 += blo(q.z); p5 += bhi(q.z); p6 += blo(q.w); p7 += bhi(q.w);

  float* rs = &red[wv][slot][grp * 8];
  rs[0] = p0; rs[1] = p1; rs[2] = p2; rs[3] = p3;
  rs[4] = p4; rs[5] = p5; rs[6] = p6; rs[7] = p7;
  __syncthreads();
  float v = 0.f;
#pragma unroll
  for (int s = 0; s < 8; ++s) v += red[wv][s][lane];
  float H1 = dinv[n] * v + b1[lane];
  A1[(size_t)n * DIM_H + lane] = f2bf(fmaxf(H1, 0.f));
}

// ---------- layer 2 GEMM (bf16 in, full K=64): h2b = bf16(dinv*(A1@W2p)) ----------
__global__ __launch_bounds__(192) void k_gemm2(const unsigned short* __restrict__ A1,
                                               const float* __restrict__ W2p,
                                               const float* __restrict__ dinv,
                                               unsigned short* __restrict__ h2b) {
  const int lane = threadIdx.x & 63;
  const int j0   = __builtin_amdgcn_readfirstlane((threadIdx.x >> 6) * 16);
  int row = blockIdx.x * 64 + lane;
  if (row >= N_NODES) row = N_NODES - 1;
  const uint4* ar = (const uint4*)(A1 + (size_t)row * DIM_H);
  uint4 av[8];
#pragma unroll
  for (int t = 0; t < 8; ++t) av[t] = ar[t];
  __builtin_amdgcn_sched_barrier(0);

  float acc[16];
#pragma unroll
  for (int j = 0; j < 16; ++j) acc[j] = 0.f;

#pragma unroll
  for (int t = 0; t < 8; ++t) {
    unsigned d4[4] = {av[t].x, av[t].y, av[t].z, av[t].w};
#pragma unroll
    for (int u = 0; u < 4; ++u) {
      int d = t * 4 + u;                      // dword 0..31 -> channels 2d, 2d+1
      float x0 = blo(d4[u]), x1 = bhi(d4[u]);
      const float* w0 = W2p + (size_t)(2 * d) * DIM_CP + j0;      // uniform -> s_load
      const float* w1 = W2p + (size_t)(2 * d + 1) * DIM_CP + j0;
#pragma unroll
      for (int j = 0; j < 16; ++j) {
        acc[j] = fmaf(x0, w0[j], acc[j]);
        acc[j] = fmaf(x1, w1[j], acc[j]);
      }
    }
  }

  float di = dinv[row];
  unsigned* outp = (unsigned*)(h2b + (size_t)row * DIM_H + j0);
#pragma unroll
  for (int p = 0; p < 8; ++p) {
    unsigned lo = f2bf(di * acc[2 * p]);
    unsigned hi = f2bf(di * acc[2 * p + 1]);
    outp[p] = lo | (hi << 16);
  }
}

// ---------- agg2 slot-gather with index prefetch + bias + fused log_softmax ----------
__global__ __launch_bounds__(256) void k_agg2_gather(const unsigned short* __restrict__ h2b,
                                                     const float* __restrict__ dinv,
                                                     const float* __restrict__ b2,
                                                     const int* __restrict__ row_start,
                                                     const int* __restrict__ cnt,
                                                     const int* __restrict__ sorted_src,
                                                     float* __restrict__ out) {
  __shared__ float red[4][8][72];             // [wave][slot][channel], padded
  const int wv   = threadIdx.x >> 6;
  const int n    = blockIdx.x * 4 + wv;       // grid exact
  const int lane = threadIdx.x & 63;
  const int slot = lane >> 3, grp = lane & 7;
  const int start = row_start[n];
  const int deg   = cnt[n];
  const int rounds = (deg + 8) >> 3;

  float p0 = 0.f, p1 = 0.f, p2 = 0.f, p3 = 0.f, p4 = 0.f, p5 = 0.f, p6 = 0.f, p7 = 0.f;
  int row0 = (slot == 0) ? n : ((slot <= deg) ? sorted_src[start + slot - 1] : N_NODES);
  int idxn = (8 + slot <= deg) ? sorted_src[start + 8 + slot - 1] : N_NODES;
  uint4 q = *((const uint4*)(h2b + (size_t)row0 * DIM_H) + grp);
  for (int r = 1; r < rounds; ++r) {
    int row = idxn;
    int kn = (r + 1) * 8 + slot;              // prefetch round r+1's index
    idxn = (kn <= deg) ? sorted_src[start + kn - 1] : N_NODES;
    uint4 qn = *((const uint4*)(h2b + (size_t)row * DIM_H) + grp);
    p0 += blo(q.x); p1 += bhi(q.x); p2 += blo(q.y); p3 += bhi(q.y);
    p4 += blo(q.z); p5 += bhi(q.z); p6 += blo(q.w); p7 += bhi(q.w);
    q = qn;
  }
  p0 += blo(q.x); p1 += bhi(q.x); p2 += blo(q.y); p3 += bhi(q.y);
  p4 += blo(q.z); p5 += bhi(q.z); p6 += blo(q.w); p7 += bhi(q.w);

  float* rs = &red[wv][slot][grp * 8];
  rs[0] = p0; rs[1] = p1; rs[2] = p2; rs[3] = p3;
  rs[4] = p4; rs[5] = p5; rs[6] = p6; rs[7] = p7;
  __syncthreads();
  float v = 0.f;
#pragma unroll
  for (int s = 0; s < 8; ++s) v += red[wv][s][lane];

  float val = (lane < DIM_C) ? (dinv[n] * v + b2[lane]) : -INFINITY;

  // fused log_softmax over the 47 classes
  float m = val;
  for (int o = 32; o; o >>= 1) m = fmaxf(m, __shfl_xor(m, o));
  float ex = (lane < DIM_C) ? __expf(val - m) : 0.0f;
  float s = ex;
  for (int o = 32; o; o >>= 1) s += __shfl_xor(s, o);
  if (lane < DIM_C) out[(size_t)n * DIM_C + lane] = val - m - __logf(s);
}

extern "C" void kernel_launch(void* const* d_in, const int* in_sizes, int n_in,
                              void* d_out, int out_size, void* d_ws, size_t ws_size,
                              hipStream_t stream) {
  const float* x  = (const float*)d_in[0];
  const float* W1 = (const float*)d_in[1];
  const float* b1 = (const float*)d_in[2];
  const float* W2 = (const float*)d_in[3];
  const float* b2 = (const float*)d_in[4];
  const int*   ei = (const int*)d_in[5];
  const int* src = ei;
  const int* dst = ei + N_EDGES;
  float* out = (float*)d_out;

  float* ws   = (float*)d_ws;
  float* dinv = ws;                                   // N floats
  float* W2p  = dinv + N_NODES;                       // 64*48 floats
  short* W1f  = (short*)(W2p + DIM_H * DIM_CP);       // 16384 shorts
  unsigned short* h1b = (unsigned short*)(W1f + 16384);      // (N+1)*64 bf16 (sentinel row)
  unsigned short* A1  = h1b + (size_t)(N_NODES + 1) * DIM_H; // N*64 bf16
  unsigned short* h2b = h1b;                          // alias: h1b dead after agg1_gather
  unsigned* chunk_buf = (unsigned*)h1b;               // alias: 7.4MB < sentinel offset 12.8MB
  int* ibuf        = (int*)(A1 + (size_t)N_NODES * DIM_H);
  int* cnt         = ibuf;                            // N
  int* row_start   = cnt + N_NODES;                   // N
  int* bucket_cur  = row_start + N_NODES;             // 8 (+pad)
  int* chunk_cur   = bucket_cur + 64;                 // 400
  int* chunk_base  = chunk_cur + NCHUNK;              // 400 (+pad)
  int* sorted_src  = chunk_base + NCHUNK + 64;        // E
  unsigned* bucket_buf = (unsigned*)(sorted_src + N_EDGES);  // NB*BCAP

  const int nblk_nw = (N_NODES + 3) / 4;              // wave-per-node gathers
  const int nblk_g1 = (N_NODES + 63) / 64;            // 64-row MFMA tiles
  const int nblk_g2 = (N_NODES + 63) / 64;            // gemm2 tiles
  const int nblk_p1 = (N_EDGES + CHUNK_P1 - 1) / CHUNK_P1;   // 782

  // fused prep (counters + W2 pad + W1 swizzle + sentinel), then CSR build
  k_prep<<<64, 256, 0, stream>>>(bucket_cur, chunk_cur, W2, W2p, W1, W1f, h1b);
  k_bin<<<nblk_p1, 256, 0, stream>>>(src, dst, bucket_cur, bucket_buf);
  k_bin2<<<NB * NSEG_P2, 256, 0, stream>>>(bucket_buf, bucket_cur, chunk_cur, chunk_buf);
  k_scan_chunks<<<1, 512, 0, stream>>>(chunk_cur, chunk_base);
  k_sort_chunk<<<NCHUNK, 256, 0, stream>>>(chunk_buf, chunk_cur, chunk_base,
                                           cnt, row_start, sorted_src, dinv);

  // layer 1 (MFMA, bf16 LDS tile, bf16 output) + slot-gather agg1 -> bf16 A1
  k_gemm1<<<nblk_g1, 256, 0, stream>>>(x, W1f, dinv, h1b);
  k_agg1_gather<<<nblk_nw, 256, 0, stream>>>(h1b, dinv, b1, row_start, cnt, sorted_src, A1);

  // layer 2 (bf16 in, 64-ch bf16 rows out) + slot-gather agg2 + fused log_softmax
  k_gemm2<<<nblk_g2, 192, 0, stream>>>(A1, W2p, dinv, h2b);
  k_agg2_gather<<<nblk_nw, 256, 0, stream>>>(h2b, dinv, b2, row_start, cnt, sorted_src, out);
}